// Round 1
// baseline (1006.201 us; speedup 1.0000x reference)
//
#include <hip/hip_runtime.h>
#include <hip/hip_bf16.h>
#include <math.h>

// Problem constants
constexpr int T_ = 1024, S_ = 1024, B_ = 4, E_ = 1024, H_ = 16, D_ = 64;
constexpr float SCALE_ = 0.125f;                 // D^-0.5
constexpr size_t NH_ = (size_t)B_ * H_ * T_ * D_; // 4,194,304 elems per head-tensor

// ---------------------------------------------------------------------------
// Generic projection GEMM: C = op( A(M,K) @ W(N,K)^T ), K = E = 1024
//   MODE 0: qh/kh layout  C[((b*H+h)*T + t)*D + d] = scale*acc   (m=t*B+b, n=h*D+d)
//   MODE 1: vhT layout    C[((b*H+h)*D + d)*S + t] = acc
//   MODE 2: final         C[m*E + n] = acc + bias[n]
// Tile 128x128, BK=32, 256 threads, 8x8 per thread. fp32 vector FMA.
// ---------------------------------------------------------------------------
template <int MODE>
__global__ __launch_bounds__(256) void proj_gemm(
    const float* __restrict__ A, const float* __restrict__ W,
    const float* __restrict__ bias, float* __restrict__ C, float scale)
{
    constexpr int BM = 128, BN = 128, BK = 32;
    constexpr int K = E_;
    __shared__ float As[BK][BM];
    __shared__ float Bs[BK][BN];

    const int m0 = blockIdx.x * BM;
    const int n0 = blockIdx.y * BN;
    const int tid = threadIdx.x;
    const int tx = tid & 15;   // m direction (8 rows each)
    const int ty = tid >> 4;   // n direction (8 cols each)

    float acc[8][8];
#pragma unroll
    for (int i = 0; i < 8; ++i)
#pragma unroll
        for (int j = 0; j < 8; ++j) acc[i][j] = 0.f;

    for (int k0 = 0; k0 < K; k0 += BK) {
        // stage A and W tiles (128 rows x 32 k) transposed into LDS
#pragma unroll
        for (int i = 0; i < 4; ++i) {
            int f = tid + i * 256;          // 0..1023
            int row = f >> 3;               // 0..127
            int kq = f & 7;                 // 0..7 (k = kq*4)
            float4 a = *(const float4*)&A[(size_t)(m0 + row) * K + k0 + kq * 4];
            As[kq * 4 + 0][row] = a.x; As[kq * 4 + 1][row] = a.y;
            As[kq * 4 + 2][row] = a.z; As[kq * 4 + 3][row] = a.w;
            float4 b = *(const float4*)&W[(size_t)(n0 + row) * K + k0 + kq * 4];
            Bs[kq * 4 + 0][row] = b.x; Bs[kq * 4 + 1][row] = b.y;
            Bs[kq * 4 + 2][row] = b.z; Bs[kq * 4 + 3][row] = b.w;
        }
        __syncthreads();
#pragma unroll
        for (int kk = 0; kk < BK; ++kk) {
            float4 a0 = *(const float4*)&As[kk][tx * 8];
            float4 a1 = *(const float4*)&As[kk][tx * 8 + 4];
            float4 b0 = *(const float4*)&Bs[kk][ty * 8];
            float4 b1 = *(const float4*)&Bs[kk][ty * 8 + 4];
            float am[8] = {a0.x, a0.y, a0.z, a0.w, a1.x, a1.y, a1.z, a1.w};
            float bn[8] = {b0.x, b0.y, b0.z, b0.w, b1.x, b1.y, b1.z, b1.w};
#pragma unroll
            for (int i = 0; i < 8; ++i)
#pragma unroll
                for (int j = 0; j < 8; ++j)
                    acc[i][j] = fmaf(am[i], bn[j], acc[i][j]);
        }
        __syncthreads();
    }

    // epilogue
#pragma unroll
    for (int i = 0; i < 8; ++i) {
        int m = m0 + tx * 8 + i;
#pragma unroll
        for (int j = 0; j < 8; ++j) {
            int n = n0 + ty * 8 + j;
            if (MODE == 0) {
                int t = m / B_, b = m % B_;
                int h = n / D_, d = n % D_;
                size_t idx = (((size_t)b * H_ + h) * T_ + t) * D_ + d;
                C[idx] = acc[i][j] * scale;
            } else if (MODE == 1) {
                int s = m / B_, b = m % B_;
                int h = n / D_, d = n % D_;
                size_t idx = (((size_t)b * H_ + h) * D_ + d) * S_ + s;
                C[idx] = acc[i][j];
            } else {
                size_t idx = (size_t)m * E_ + n;
                C[idx] = acc[i][j] + bias[n];
            }
        }
    }
}

// ---------------------------------------------------------------------------
// Scores GEMM per (b,h): scores[t,s] = sum_d qh[t,d]*kh[s,d] + bias[t,s]
// qh already carries SCALE. Writes into the attn output region.
// ---------------------------------------------------------------------------
__global__ __launch_bounds__(256) void scores_gemm(
    const float* __restrict__ qh, const float* __restrict__ kh,
    const float* __restrict__ attn_bias, float* __restrict__ scores)
{
    constexpr int BM = 128, BN = 128, BK = 32;
    constexpr int K = D_;
    __shared__ float As[BK][BM];
    __shared__ float Bs[BK][BN];

    const int bh = blockIdx.z;
    const float* Aq = qh + (size_t)bh * T_ * D_;
    const float* Bk = kh + (size_t)bh * S_ * D_;

    const int m0 = blockIdx.x * BM;
    const int n0 = blockIdx.y * BN;
    const int tid = threadIdx.x;
    const int tx = tid & 15;
    const int ty = tid >> 4;

    float acc[8][8];
#pragma unroll
    for (int i = 0; i < 8; ++i)
#pragma unroll
        for (int j = 0; j < 8; ++j) acc[i][j] = 0.f;

    for (int k0 = 0; k0 < K; k0 += BK) {
#pragma unroll
        for (int i = 0; i < 4; ++i) {
            int f = tid + i * 256;
            int row = f >> 3;
            int kq = f & 7;
            float4 a = *(const float4*)&Aq[(size_t)(m0 + row) * D_ + k0 + kq * 4];
            As[kq * 4 + 0][row] = a.x; As[kq * 4 + 1][row] = a.y;
            As[kq * 4 + 2][row] = a.z; As[kq * 4 + 3][row] = a.w;
            float4 b = *(const float4*)&Bk[(size_t)(n0 + row) * D_ + k0 + kq * 4];
            Bs[kq * 4 + 0][row] = b.x; Bs[kq * 4 + 1][row] = b.y;
            Bs[kq * 4 + 2][row] = b.z; Bs[kq * 4 + 3][row] = b.w;
        }
        __syncthreads();
#pragma unroll
        for (int kk = 0; kk < BK; ++kk) {
            float4 a0 = *(const float4*)&As[kk][tx * 8];
            float4 a1 = *(const float4*)&As[kk][tx * 8 + 4];
            float4 b0 = *(const float4*)&Bs[kk][ty * 8];
            float4 b1 = *(const float4*)&Bs[kk][ty * 8 + 4];
            float am[8] = {a0.x, a0.y, a0.z, a0.w, a1.x, a1.y, a1.z, a1.w};
            float bn[8] = {b0.x, b0.y, b0.z, b0.w, b1.x, b1.y, b1.z, b1.w};
#pragma unroll
            for (int i = 0; i < 8; ++i)
#pragma unroll
                for (int j = 0; j < 8; ++j)
                    acc[i][j] = fmaf(am[i], bn[j], acc[i][j]);
        }
        __syncthreads();
    }

#pragma unroll
    for (int i = 0; i < 8; ++i) {
        int t = m0 + tx * 8 + i;
#pragma unroll
        for (int j = 0; j < 8; ++j) {
            int s = n0 + ty * 8 + j;
            size_t idx = ((size_t)bh * T_ + t) * S_ + s;
            scores[idx] = acc[i][j] + attn_bias[idx];
        }
    }
}

// ---------------------------------------------------------------------------
// Masked softmax, in place over attn rows of length S=1024.
// mask[b][s] nonzero => masked => attn = 0, excluded from max/sum.
// One block (256 thr) per row; 4 elements per thread.
// ---------------------------------------------------------------------------
__global__ __launch_bounds__(256) void softmax_kernel(
    float* __restrict__ attn, const int* __restrict__ mask)
{
    const size_t row = blockIdx.x;               // 0 .. B*H*T-1
    const int b = (int)(row / ((size_t)H_ * T_));
    float* p = attn + row * S_;
    const int* mrow = mask + (size_t)b * S_;

    const int tid = threadIdx.x;
    const int lane = tid & 63;
    const int wv = tid >> 6;

    float4 v = *(const float4*)&p[tid * 4];
    int4 mm = *(const int4*)&mrow[tid * 4];

    float mx = -3.402823466e+38f;
    if (!mm.x) mx = v.x;
    if (!mm.y) mx = fmaxf(mx, v.y);
    if (!mm.z) mx = fmaxf(mx, v.z);
    if (!mm.w) mx = fmaxf(mx, v.w);

#pragma unroll
    for (int off = 1; off < 64; off <<= 1) mx = fmaxf(mx, __shfl_xor(mx, off));

    __shared__ float redmax[4];
    __shared__ float redsum[4];
    if (lane == 0) redmax[wv] = mx;
    __syncthreads();
    mx = fmaxf(fmaxf(redmax[0], redmax[1]), fmaxf(redmax[2], redmax[3]));

    float4 e;
    e.x = mm.x ? 0.f : expf(v.x - mx);
    e.y = mm.y ? 0.f : expf(v.y - mx);
    e.z = mm.z ? 0.f : expf(v.z - mx);
    e.w = mm.w ? 0.f : expf(v.w - mx);
    float sm = e.x + e.y + e.z + e.w;

#pragma unroll
    for (int off = 1; off < 64; off <<= 1) sm += __shfl_xor(sm, off);
    if (lane == 0) redsum[wv] = sm;
    __syncthreads();
    float tot = redsum[0] + redsum[1] + redsum[2] + redsum[3];
    float inv = 1.0f / tot;

    e.x *= inv; e.y *= inv; e.z *= inv; e.w *= inv;
    *(float4*)&p[tid * 4] = e;
}

// ---------------------------------------------------------------------------
// PV GEMM per (b,h): oh_tbe[t, b, h*D+d] = sum_s attn[t,s] * vhT[d,s]
// BM=128, BN=64, BK=32, 256 threads, 8x4 per thread.
// ---------------------------------------------------------------------------
__global__ __launch_bounds__(256) void pv_gemm(
    const float* __restrict__ attn, const float* __restrict__ vhT,
    float* __restrict__ oh)
{
    constexpr int BM = 128, BN = 64, BK = 32;
    __shared__ float As[BK][BM];
    __shared__ float Bs[BK][BN];

    const int bh = blockIdx.z;
    const int b = bh >> 4;        // bh / H_
    const int h = bh & 15;        // bh % H_
    const float* Aa = attn + (size_t)bh * T_ * S_;
    const float* Bv = vhT + (size_t)bh * D_ * S_;

    const int m0 = blockIdx.x * BM;
    const int tid = threadIdx.x;
    const int tx = tid & 15;   // m (8 each)
    const int ty = tid >> 4;   // n (4 each)

    float acc[8][4];
#pragma unroll
    for (int i = 0; i < 8; ++i)
#pragma unroll
        for (int j = 0; j < 4; ++j) acc[i][j] = 0.f;

    for (int k0 = 0; k0 < S_; k0 += BK) {
        // A tile: 128 x 32
#pragma unroll
        for (int i = 0; i < 4; ++i) {
            int f = tid + i * 256;
            int row = f >> 3;
            int kq = f & 7;
            float4 a = *(const float4*)&Aa[(size_t)(m0 + row) * S_ + k0 + kq * 4];
            As[kq * 4 + 0][row] = a.x; As[kq * 4 + 1][row] = a.y;
            As[kq * 4 + 2][row] = a.z; As[kq * 4 + 3][row] = a.w;
        }
        // B tile: 64 x 32
#pragma unroll
        for (int i = 0; i < 2; ++i) {
            int f = tid + i * 256;
            int row = f >> 3;   // 0..63
            int kq = f & 7;
            float4 bv = *(const float4*)&Bv[(size_t)row * S_ + k0 + kq * 4];
            Bs[kq * 4 + 0][row] = bv.x; Bs[kq * 4 + 1][row] = bv.y;
            Bs[kq * 4 + 2][row] = bv.z; Bs[kq * 4 + 3][row] = bv.w;
        }
        __syncthreads();
#pragma unroll
        for (int kk = 0; kk < BK; ++kk) {
            float4 a0 = *(const float4*)&As[kk][tx * 8];
            float4 a1 = *(const float4*)&As[kk][tx * 8 + 4];
            float4 b0 = *(const float4*)&Bs[kk][ty * 4];
            float am[8] = {a0.x, a0.y, a0.z, a0.w, a1.x, a1.y, a1.z, a1.w};
            float bn[4] = {b0.x, b0.y, b0.z, b0.w};
#pragma unroll
            for (int i = 0; i < 8; ++i)
#pragma unroll
                for (int j = 0; j < 4; ++j)
                    acc[i][j] = fmaf(am[i], bn[j], acc[i][j]);
        }
        __syncthreads();
    }

#pragma unroll
    for (int i = 0; i < 8; ++i) {
        int t = m0 + tx * 8 + i;
#pragma unroll
        for (int j = 0; j < 4; ++j) {
            int d = ty * 4 + j;
            size_t idx = ((size_t)t * B_ + b) * E_ + h * D_ + d;
            oh[idx] = acc[i][j];
        }
    }
}

// ---------------------------------------------------------------------------
extern "C" void kernel_launch(void* const* d_in, const int* in_sizes, int n_in,
                              void* d_out, int out_size, void* d_ws, size_t ws_size,
                              hipStream_t stream)
{
    const float* q    = (const float*)d_in[0];
    const float* k    = (const float*)d_in[1];
    const float* v    = (const float*)d_in[2];
    const float* Wq   = (const float*)d_in[3];
    const float* Wk   = (const float*)d_in[4];
    const float* Wv   = (const float*)d_in[5];
    const float* Wp   = (const float*)d_in[6];
    const float* bp   = (const float*)d_in[7];
    const float* bias = (const float*)d_in[8];
    const int*   mask = (const int*)d_in[9];

    float* out  = (float*)d_out;                          // (T,B,E)
    float* attn = out + (size_t)T_ * B_ * E_;             // (B,H,T,S)

    float* qh  = (float*)d_ws;         // (B,H,T,D)
    float* kh  = qh + NH_;             // (B,H,S,D)
    float* vhT = kh + NH_;             // (B,H,D,S)
    float* oh  = vhT + NH_;            // (T,B,E)

    dim3 blk(256);

    // Projections: M = T*B = 4096 rows, N = E = 1024
    proj_gemm<0><<<dim3(32, 8), blk, 0, stream>>>(q, Wq, nullptr, qh, SCALE_);
    proj_gemm<0><<<dim3(32, 8), blk, 0, stream>>>(k, Wk, nullptr, kh, 1.0f);
    proj_gemm<1><<<dim3(32, 8), blk, 0, stream>>>(v, Wv, nullptr, vhT, 1.0f);

    // Scores + bias -> attn buffer
    scores_gemm<<<dim3(8, 8, B_ * H_), blk, 0, stream>>>(qh, kh, bias, attn);

    // Masked softmax in place
    softmax_kernel<<<dim3(B_ * H_ * T_), blk, 0, stream>>>(attn, mask);

    // PV -> oh (T,B,E)
    pv_gemm<<<dim3(8, 1, B_ * H_), blk, 0, stream>>>(attn, vhT, oh);

    // Output projection + bias
    proj_gemm<2><<<dim3(32, 8), blk, 0, stream>>>(oh, Wp, bp, out, 1.0f);
}

// Round 2
// 616.448 us; speedup vs baseline: 1.6323x; 1.6323x over previous
//
#include <hip/hip_runtime.h>
#include <math.h>

// Problem constants
constexpr int T_ = 1024, S_ = 1024, B_ = 4, E_ = 1024, H_ = 16, D_ = 64;
constexpr float SCALE_ = 0.125f;                  // D^-0.5
constexpr size_t NH_ = (size_t)B_ * H_ * T_ * D_; // 4,194,304 elems

typedef _Float16 h8 __attribute__((ext_vector_type(8)));
typedef float f4 __attribute__((ext_vector_type(4)));

__device__ inline f4 mfma16(h8 a, h8 b, f4 c) {
    return __builtin_amdgcn_mfma_f32_16x16x32_f16(a, b, c, 0, 0, 0);
}

// ---------------------------------------------------------------------------
// Projection GEMM via MFMA f16: C = A(M=4096,K=1024) @ W(N=1024,K)^T
//   MODE 0: qh/kh (B,H,T,D) f16, *scale     MODE 1: vhT (B,H,D,S) f16
//   MODE 2: out (M,N) f32 + bias
// 128x128 tile, BK=64, 512 thr = 8 waves (2x4), wave tile 64x32.
// A staged f32->f16 (or f16 direct when AHALF), W staged f32->f16.
// ---------------------------------------------------------------------------
template <int MODE, bool AHALF>
__global__ __launch_bounds__(512) void proj_gemm(
    const void* __restrict__ Av, const float* __restrict__ W,
    const float* __restrict__ bias, void* __restrict__ Cv, float scale)
{
    __shared__ _Float16 As[128][72];   // 72 = 64 + 8 pad (row stride 144B, 16B-aligned)
    __shared__ _Float16 Bs[128][72];

    const int m0 = blockIdx.x * 128, n0 = blockIdx.y * 128;
    const int tid = threadIdx.x;
    const int w = tid >> 6, l = tid & 63, lr = l & 15, lg = l >> 4;
    const int wr = w >> 2, wc = w & 3;

    f4 acc[4][2];
#pragma unroll
    for (int mi = 0; mi < 4; ++mi)
#pragma unroll
        for (int ni = 0; ni < 2; ++ni) acc[mi][ni] = (f4){0.f, 0.f, 0.f, 0.f};

    const float* Af = (const float*)Av;
    const _Float16* Ah = (const _Float16*)Av;

    for (int k0 = 0; k0 < 1024; k0 += 64) {
        // ---- stage A and W tiles into LDS as f16 ----
#pragma unroll
        for (int i = 0; i < 2; ++i) {
            int f = tid + i * 512;          // 0..1023
            int row = f >> 3, c = f & 7;    // row 0..127, chunk of 8 k
            if (AHALF) {
                *(h8*)&As[row][c * 8] =
                    *(const h8*)&Ah[(size_t)(m0 + row) * 1024 + k0 + c * 8];
            } else {
                const float* p = &Af[(size_t)(m0 + row) * 1024 + k0 + c * 8];
                float4 x0 = *(const float4*)p;
                float4 x1 = *(const float4*)(p + 4);
                h8 va;
                va[0] = (_Float16)x0.x; va[1] = (_Float16)x0.y;
                va[2] = (_Float16)x0.z; va[3] = (_Float16)x0.w;
                va[4] = (_Float16)x1.x; va[5] = (_Float16)x1.y;
                va[6] = (_Float16)x1.z; va[7] = (_Float16)x1.w;
                *(h8*)&As[row][c * 8] = va;
            }
            const float* pw = &W[(size_t)(n0 + row) * 1024 + k0 + c * 8];
            float4 y0 = *(const float4*)pw;
            float4 y1 = *(const float4*)(pw + 4);
            h8 vb;
            vb[0] = (_Float16)y0.x; vb[1] = (_Float16)y0.y;
            vb[2] = (_Float16)y0.z; vb[3] = (_Float16)y0.w;
            vb[4] = (_Float16)y1.x; vb[5] = (_Float16)y1.y;
            vb[6] = (_Float16)y1.z; vb[7] = (_Float16)y1.w;
            *(h8*)&Bs[row][c * 8] = vb;
        }
        __syncthreads();
        // ---- MFMA over BK=64 (two k=32 steps) ----
#pragma unroll
        for (int kk = 0; kk < 2; ++kk) {
            h8 af[4], bf[2];
#pragma unroll
            for (int mi = 0; mi < 4; ++mi)
                af[mi] = *(const h8*)&As[wr * 64 + mi * 16 + lr][kk * 32 + lg * 8];
#pragma unroll
            for (int ni = 0; ni < 2; ++ni)
                bf[ni] = *(const h8*)&Bs[wc * 32 + ni * 16 + lr][kk * 32 + lg * 8];
#pragma unroll
            for (int mi = 0; mi < 4; ++mi)
#pragma unroll
                for (int ni = 0; ni < 2; ++ni)
                    acc[mi][ni] = mfma16(af[mi], bf[ni], acc[mi][ni]);
        }
        __syncthreads();
    }

    // ---- epilogue: C/D layout col=lane&15, row=(lane>>4)*4+reg ----
#pragma unroll
    for (int mi = 0; mi < 4; ++mi)
#pragma unroll
        for (int ni = 0; ni < 2; ++ni)
#pragma unroll
            for (int r = 0; r < 4; ++r) {
                int row = m0 + wr * 64 + mi * 16 + lg * 4 + r;
                int col = n0 + wc * 32 + ni * 16 + lr;
                float vv = acc[mi][ni][r] * scale;
                if (MODE == 0) {
                    int t = row >> 2, b = row & 3, h = col >> 6, d = col & 63;
                    ((_Float16*)Cv)[(((size_t)b * H_ + h) * T_ + t) * D_ + d] = (_Float16)vv;
                } else if (MODE == 1) {
                    int s = row >> 2, b = row & 3, h = col >> 6, d = col & 63;
                    ((_Float16*)Cv)[(((size_t)b * H_ + h) * D_ + d) * S_ + s] = (_Float16)vv;
                } else {
                    ((float*)Cv)[(size_t)row * E_ + col] = vv + bias[col];
                }
            }
}

// ---------------------------------------------------------------------------
// Scores: P_unnorm = mask ? 0 : exp(qh·kh^T + bias)  (qh pre-scaled)
// Writes unnormalized attn + per-row sums. Softmax shift-invariance lets us
// skip the max pass (scores are O(±3)).
// grid (T/128, BH), 512 thr = 8 waves; wave w owns t-rows [w*16, w*16+16).
// ---------------------------------------------------------------------------
__global__ __launch_bounds__(512) void scores_kernel(
    const _Float16* __restrict__ qh, const _Float16* __restrict__ kh,
    const float* __restrict__ bias, const int* __restrict__ mask,
    float* __restrict__ attn, float* __restrict__ rowsum)
{
    const int bh = blockIdx.y;
    const int b = bh >> 4;
    const int t0 = blockIdx.x * 128;
    const int tid = threadIdx.x;
    const int w = tid >> 6, l = tid & 63, lr = l & 15, lg = l >> 4;
    const int tw = t0 + w * 16;

    __shared__ int smask[S_];
    for (int i = tid; i < S_; i += 512) smask[i] = mask[(size_t)b * S_ + i];
    __syncthreads();

    // A-frags: lane holds qh[t = tw + lr][k = lg*8 .. +8) (+32 for second)
    const _Float16* qbase = qh + ((size_t)bh * T_ + tw) * D_;
    h8 a0 = *(const h8*)&qbase[(size_t)lr * D_ + lg * 8];
    h8 a1 = *(const h8*)&qbase[(size_t)lr * D_ + 32 + lg * 8];

    const _Float16* kbase = kh + (size_t)bh * S_ * D_;
    const float* bbase = bias + (size_t)bh * T_ * S_;
    float* abase = attn + (size_t)bh * T_ * S_;

    float rs[4] = {0.f, 0.f, 0.f, 0.f};

    for (int s0 = 0; s0 < S_; s0 += 16) {
        h8 b0 = *(const h8*)&kbase[(size_t)(s0 + lr) * D_ + lg * 8];
        h8 b1 = *(const h8*)&kbase[(size_t)(s0 + lr) * D_ + 32 + lg * 8];
        f4 c = (f4){0.f, 0.f, 0.f, 0.f};
        c = mfma16(a0, b0, c);
        c = mfma16(a1, b1, c);
        int msk = smask[s0 + lr];
#pragma unroll
        for (int r = 0; r < 4; ++r) {
            int t = tw + lg * 4 + r;
            float p = c[r] + bbase[(size_t)t * S_ + s0 + lr];
            float ev = msk ? 0.f : __expf(p);
            rs[r] += ev;
            abase[(size_t)t * S_ + s0 + lr] = ev;
        }
    }
    // reduce over the 16 col-lanes (low 4 bits of lane id)
#pragma unroll
    for (int off = 1; off < 16; off <<= 1)
#pragma unroll
        for (int r = 0; r < 4; ++r) rs[r] += __shfl_xor(rs[r], off);
    if (lr == 0) {
#pragma unroll
        for (int r = 0; r < 4; ++r)
            rowsum[(size_t)bh * T_ + tw + lg * 4 + r] = rs[r];
    }
}

// ---------------------------------------------------------------------------
// PV + normalize: reads unnormalized attn, scales by 1/rowsum, writes the
// final normalized attn in place, and accumulates O = P_norm @ V via MFMA.
// grid (T/128, BH), 512 thr = 8 waves; wave owns 16 t-rows x full D=64.
// ---------------------------------------------------------------------------
__global__ __launch_bounds__(512) void pv_kernel(
    float* __restrict__ attn, const _Float16* __restrict__ vhT,
    const float* __restrict__ rowsum, _Float16* __restrict__ oh)
{
    const int bh = blockIdx.y;
    const int b = bh >> 4, h = bh & 15;
    const int t0 = blockIdx.x * 128;
    const int tid = threadIdx.x;
    const int w = tid >> 6, l = tid & 63, lr = l & 15, lg = l >> 4;
    const int tw = t0 + w * 16;

    const float inv = 1.0f / rowsum[(size_t)bh * T_ + tw + lr];  // A-frag row = lr
    float* abase = attn + ((size_t)bh * T_ + tw) * S_;
    const _Float16* vbase = vhT + (size_t)bh * D_ * S_;

    f4 acc[4];
#pragma unroll
    for (int n = 0; n < 4; ++n) acc[n] = (f4){0.f, 0.f, 0.f, 0.f};

    for (int s0 = 0; s0 < S_; s0 += 32) {
        size_t off = (size_t)lr * S_ + s0 + lg * 8;
        float4 p0 = *(const float4*)&abase[off];
        float4 p1 = *(const float4*)&abase[off + 4];
        p0.x *= inv; p0.y *= inv; p0.z *= inv; p0.w *= inv;
        p1.x *= inv; p1.y *= inv; p1.z *= inv; p1.w *= inv;
        *(float4*)&abase[off] = p0;          // final normalized attn
        *(float4*)&abase[off + 4] = p1;
        h8 a;
        a[0] = (_Float16)p0.x; a[1] = (_Float16)p0.y;
        a[2] = (_Float16)p0.z; a[3] = (_Float16)p0.w;
        a[4] = (_Float16)p1.x; a[5] = (_Float16)p1.y;
        a[6] = (_Float16)p1.z; a[7] = (_Float16)p1.w;
#pragma unroll
        for (int n = 0; n < 4; ++n) {
            h8 bf = *(const h8*)&vbase[(size_t)(n * 16 + lr) * S_ + s0 + lg * 8];
            acc[n] = mfma16(a, bf, acc[n]);
        }
    }
    // O write: row t = tw + lg*4 + r, col d = n*16 + lr, into (T,B,E) f16
#pragma unroll
    for (int n = 0; n < 4; ++n)
#pragma unroll
        for (int r = 0; r < 4; ++r) {
            int t = tw + lg * 4 + r;
            oh[((size_t)t * B_ + b) * E_ + h * D_ + n * 16 + lr] = (_Float16)acc[n][r];
        }
}

// ---------------------------------------------------------------------------
extern "C" void kernel_launch(void* const* d_in, const int* in_sizes, int n_in,
                              void* d_out, int out_size, void* d_ws, size_t ws_size,
                              hipStream_t stream)
{
    const float* q    = (const float*)d_in[0];
    const float* k    = (const float*)d_in[1];
    const float* v    = (const float*)d_in[2];
    const float* Wq   = (const float*)d_in[3];
    const float* Wk   = (const float*)d_in[4];
    const float* Wv   = (const float*)d_in[5];
    const float* Wp   = (const float*)d_in[6];
    const float* bp   = (const float*)d_in[7];
    const float* bias = (const float*)d_in[8];
    const int*   mask = (const int*)d_in[9];

    float* out  = (float*)d_out;               // (T,B,E) f32
    float* attn = out + (size_t)T_ * B_ * E_;  // (B,H,T,S) f32

    _Float16* qh  = (_Float16*)d_ws;           // (B,H,T,D)
    _Float16* kh  = qh + NH_;                  // (B,H,S,D)
    _Float16* vhT = kh + NH_;                  // (B,H,D,S)
    _Float16* oh  = vhT + NH_;                 // (T,B,E)
    float* rowsum = (float*)(oh + NH_);        // (BH, T)

    dim3 blk(512);

    proj_gemm<0, false><<<dim3(32, 8), blk, 0, stream>>>(q, Wq, nullptr, qh, SCALE_);
    proj_gemm<0, false><<<dim3(32, 8), blk, 0, stream>>>(k, Wk, nullptr, kh, 1.0f);
    proj_gemm<1, false><<<dim3(32, 8), blk, 0, stream>>>(v, Wv, nullptr, vhT, 1.0f);

    scores_kernel<<<dim3(8, 64), blk, 0, stream>>>(qh, kh, bias, mask, attn, rowsum);

    pv_kernel<<<dim3(8, 64), blk, 0, stream>>>(attn, vhT, rowsum, oh);

    proj_gemm<2, true><<<dim3(32, 8), blk, 0, stream>>>(oh, Wp, bp, out, 1.0f);
}

// Round 3
// 438.205 us; speedup vs baseline: 2.2962x; 1.4068x over previous
//
#include <hip/hip_runtime.h>
#include <math.h>

// Problem constants
constexpr int T_ = 1024, S_ = 1024, B_ = 4, E_ = 1024, H_ = 16, D_ = 64;
constexpr float SCALE_ = 0.125f;                  // D^-0.5
constexpr size_t NH_ = (size_t)B_ * H_ * T_ * D_; // 4,194,304 elems

typedef _Float16 h8 __attribute__((ext_vector_type(8)));
typedef _Float16 h4 __attribute__((ext_vector_type(4)));
typedef float f4 __attribute__((ext_vector_type(4)));

__device__ inline f4 mfma16(h8 a, h8 b, f4 c) {
    return __builtin_amdgcn_mfma_f32_16x16x32_f16(a, b, c, 0, 0, 0);
}

// ---------------------------------------------------------------------------
// Projection GEMM via MFMA f16: C = A(M=4096,K=1024) @ W(N=1024,K)^T
//   MODE 0: qh/kh (B,H,T,D) f16, *scale     MODE 1: vhT (B,H,D,S) f16
//   MODE 2: out (M,N) f32 + bias
// 128x128 tile, BK=64, 512 thr = 8 waves (2x4), wave tile 64x32.
// ---------------------------------------------------------------------------
template <int MODE, bool AHALF>
__global__ __launch_bounds__(512) void proj_gemm(
    const void* __restrict__ Av, const float* __restrict__ W,
    const float* __restrict__ bias, void* __restrict__ Cv, float scale)
{
    __shared__ _Float16 As[128][72];   // +8 pad
    __shared__ _Float16 Bs[128][72];

    const int m0 = blockIdx.x * 128, n0 = blockIdx.y * 128;
    const int tid = threadIdx.x;
    const int w = tid >> 6, l = tid & 63, lr = l & 15, lg = l >> 4;
    const int wr = w >> 2, wc = w & 3;

    f4 acc[4][2];
#pragma unroll
    for (int mi = 0; mi < 4; ++mi)
#pragma unroll
        for (int ni = 0; ni < 2; ++ni) acc[mi][ni] = (f4){0.f, 0.f, 0.f, 0.f};

    const float* Af = (const float*)Av;
    const _Float16* Ah = (const _Float16*)Av;

    for (int k0 = 0; k0 < 1024; k0 += 64) {
#pragma unroll
        for (int i = 0; i < 2; ++i) {
            int f = tid + i * 512;
            int row = f >> 3, c = f & 7;
            if (AHALF) {
                *(h8*)&As[row][c * 8] =
                    *(const h8*)&Ah[(size_t)(m0 + row) * 1024 + k0 + c * 8];
            } else {
                const float* p = &Af[(size_t)(m0 + row) * 1024 + k0 + c * 8];
                float4 x0 = *(const float4*)p;
                float4 x1 = *(const float4*)(p + 4);
                h8 va;
                va[0] = (_Float16)x0.x; va[1] = (_Float16)x0.y;
                va[2] = (_Float16)x0.z; va[3] = (_Float16)x0.w;
                va[4] = (_Float16)x1.x; va[5] = (_Float16)x1.y;
                va[6] = (_Float16)x1.z; va[7] = (_Float16)x1.w;
                *(h8*)&As[row][c * 8] = va;
            }
            const float* pw = &W[(size_t)(n0 + row) * 1024 + k0 + c * 8];
            float4 y0 = *(const float4*)pw;
            float4 y1 = *(const float4*)(pw + 4);
            h8 vb;
            vb[0] = (_Float16)y0.x; vb[1] = (_Float16)y0.y;
            vb[2] = (_Float16)y0.z; vb[3] = (_Float16)y0.w;
            vb[4] = (_Float16)y1.x; vb[5] = (_Float16)y1.y;
            vb[6] = (_Float16)y1.z; vb[7] = (_Float16)y1.w;
            *(h8*)&Bs[row][c * 8] = vb;
        }
        __syncthreads();
#pragma unroll
        for (int kk = 0; kk < 2; ++kk) {
            h8 af[4], bf[2];
#pragma unroll
            for (int mi = 0; mi < 4; ++mi)
                af[mi] = *(const h8*)&As[wr * 64 + mi * 16 + lr][kk * 32 + lg * 8];
#pragma unroll
            for (int ni = 0; ni < 2; ++ni)
                bf[ni] = *(const h8*)&Bs[wc * 32 + ni * 16 + lr][kk * 32 + lg * 8];
#pragma unroll
            for (int mi = 0; mi < 4; ++mi)
#pragma unroll
                for (int ni = 0; ni < 2; ++ni)
                    acc[mi][ni] = mfma16(af[mi], bf[ni], acc[mi][ni]);
        }
        __syncthreads();
    }

#pragma unroll
    for (int mi = 0; mi < 4; ++mi)
#pragma unroll
        for (int ni = 0; ni < 2; ++ni)
#pragma unroll
            for (int r = 0; r < 4; ++r) {
                int row = m0 + wr * 64 + mi * 16 + lg * 4 + r;
                int col = n0 + wc * 32 + ni * 16 + lr;
                float vv = acc[mi][ni][r] * scale;
                if (MODE == 0) {
                    int t = row >> 2, b = row & 3, h = col >> 6, d = col & 63;
                    ((_Float16*)Cv)[(((size_t)b * H_ + h) * T_ + t) * D_ + d] = (_Float16)vv;
                } else if (MODE == 1) {
                    int s = row >> 2, b = row & 3, h = col >> 6, d = col & 63;
                    ((_Float16*)Cv)[(((size_t)b * H_ + h) * D_ + d) * S_ + s] = (_Float16)vv;
                } else {
                    ((float*)Cv)[(size_t)row * E_ + col] = vv + bias[col];
                }
            }
}

// ---------------------------------------------------------------------------
// Fused attention: per (bh, 32-row t-tile):
//   phase 1: P = exp(K·Q^T + bias^T) masked (swapped MFMA: col=t, row=s),
//            stored unnormalized f16 in swizzled LDS; per-row sums.
//   phase 2: attn = P * inv  (f32, coalesced 128B rows)
//   phase 3: O = (P @ V) * inv via MFMA, written to oh (T,B,E) f16.
// 512 thr = 8 waves. LDS: 64KB P + 4KB mask.
// ---------------------------------------------------------------------------
__global__ __launch_bounds__(512) void fused_attn(
    const _Float16* __restrict__ qh, const _Float16* __restrict__ kh,
    const _Float16* __restrict__ vhT, const float* __restrict__ bias,
    const int* __restrict__ mask, float* __restrict__ attn,
    _Float16* __restrict__ oh)
{
    __shared__ _Float16 Pf[32 * 1024];   // swizzled
    __shared__ int smask[S_];
    __shared__ float wsum[8][32];
    __shared__ float sinv[32];
    char* Pb = (char*)Pf;

    const int bh = blockIdx.y;
    const int b = bh >> 4, h = bh & 15;
    const int t0 = blockIdx.x * 32;
    const int tid = threadIdx.x;
    const int w = tid >> 6, l = tid & 63, lr = l & 15, lg = l >> 4;

    for (int i = tid; i < S_; i += 512) smask[i] = mask[(size_t)b * S_ + i];

    // Q fragments (B-operand): rows t = f*16+lr, elems k
    const _Float16* qbase = qh + ((size_t)bh * T_ + t0) * D_;
    h8 qf[2][2];
#pragma unroll
    for (int f = 0; f < 2; ++f)
#pragma unroll
        for (int kk = 0; kk < 2; ++kk)
            qf[f][kk] = *(const h8*)&qbase[(size_t)(f * 16 + lr) * D_ + kk * 32 + lg * 8];

    __syncthreads();

    const _Float16* kbase = kh + (size_t)bh * S_ * D_;
    const float* bbase = bias + ((size_t)bh * T_ + t0) * S_;
    const int wbase = w * 128;          // this wave's s-stripe

    float rs0 = 0.f, rs1 = 0.f;
#pragma unroll
    for (int sub = 0; sub < 8; ++sub) {
        int s0 = wbase + sub * 16;
        h8 kf0 = *(const h8*)&kbase[(size_t)(s0 + lr) * D_ + lg * 8];
        h8 kf1 = *(const h8*)&kbase[(size_t)(s0 + lr) * D_ + 32 + lg * 8];
        int4 mv = *(const int4*)&smask[s0 + lg * 4];
#pragma unroll
        for (int f = 0; f < 2; ++f) {
            f4 c = (f4){0.f, 0.f, 0.f, 0.f};
            c = mfma16(kf0, qf[f][0], c);
            c = mfma16(kf1, qf[f][1], c);
            int t = f * 16 + lr;        // col = t, rows = s0+lg*4+r
            float4 bv = *(const float4*)&bbase[(size_t)t * S_ + s0 + lg * 4];
            float e0 = mv.x ? 0.f : __expf(c[0] + bv.x);
            float e1 = mv.y ? 0.f : __expf(c[1] + bv.y);
            float e2 = mv.z ? 0.f : __expf(c[2] + bv.z);
            float e3 = mv.w ? 0.f : __expf(c[3] + bv.w);
            if (f == 0) rs0 += (e0 + e1) + (e2 + e3);
            else        rs1 += (e0 + e1) + (e2 + e3);
            h4 pv;
            pv[0] = (_Float16)e0; pv[1] = (_Float16)e1;
            pv[2] = (_Float16)e2; pv[3] = (_Float16)e3;
            int off = (t * 2048 + (s0 + lg * 4) * 2) ^ ((t & 7) << 4);
            *(h4*)(Pb + off) = pv;
        }
    }
    // reduce partial sums across lg (lane bits 4,5)
    rs0 += __shfl_xor(rs0, 16); rs0 += __shfl_xor(rs0, 32);
    rs1 += __shfl_xor(rs1, 16); rs1 += __shfl_xor(rs1, 32);
    if (l < 16) { wsum[w][lr] = rs0; wsum[w][16 + lr] = rs1; }
    __syncthreads();
    if (tid < 32) {
        float s = 0.f;
#pragma unroll
        for (int ww = 0; ww < 8; ++ww) s += wsum[ww][tid];
        sinv[tid] = 1.0f / s;
    }
    __syncthreads();

    // ---- normalized attn write (f32, 128B-coalesced rows) ----
    {
        int rr = tid & 31, hf = tid >> 5;           // row, 64-col chunk
        float inv = sinv[rr];
        float* arow = attn + ((size_t)bh * T_ + t0 + rr) * S_ + hf * 64;
#pragma unroll
        for (int j = 0; j < 8; ++j) {
            int off = (rr * 2048 + (hf * 64 + j * 8) * 2) ^ ((rr & 7) << 4);
            h8 p = *(const h8*)(Pb + off);
            float4 o0 = {(float)p[0] * inv, (float)p[1] * inv,
                         (float)p[2] * inv, (float)p[3] * inv};
            float4 o1 = {(float)p[4] * inv, (float)p[5] * inv,
                         (float)p[6] * inv, (float)p[7] * inv};
            *(float4*)&arow[j * 8] = o0;
            *(float4*)&arow[j * 8 + 4] = o1;
        }
    }

    // ---- PV: wave = 16t x 16d tile; O row t scaled by inv ----
    {
        const int tw = (w & 1) * 16, dbase = (w >> 1) * 16;
        const _Float16* vbase = vhT + (size_t)bh * D_ * S_;
        f4 acc = (f4){0.f, 0.f, 0.f, 0.f};
#pragma unroll 4
        for (int kc = 0; kc < 32; ++kc) {
            int t = tw + lr;
            int off = (t * 2048 + (kc * 32 + lg * 8) * 2) ^ ((t & 7) << 4);
            h8 pf = *(const h8*)(Pb + off);
            h8 vf = *(const h8*)&vbase[(size_t)(dbase + lr) * S_ + kc * 32 + lg * 8];
            acc = mfma16(pf, vf, acc);
        }
#pragma unroll
        for (int r = 0; r < 4; ++r) {
            int t = tw + lg * 4 + r;
            float inv = sinv[t];
            oh[((size_t)(t0 + t) * B_ + b) * E_ + h * 64 + dbase + lr] =
                (_Float16)(acc[r] * inv);
        }
    }
}

// ---------------------------------------------------------------------------
extern "C" void kernel_launch(void* const* d_in, const int* in_sizes, int n_in,
                              void* d_out, int out_size, void* d_ws, size_t ws_size,
                              hipStream_t stream)
{
    const float* q    = (const float*)d_in[0];
    const float* k    = (const float*)d_in[1];
    const float* v    = (const float*)d_in[2];
    const float* Wq   = (const float*)d_in[3];
    const float* Wk   = (const float*)d_in[4];
    const float* Wv   = (const float*)d_in[5];
    const float* Wp   = (const float*)d_in[6];
    const float* bp   = (const float*)d_in[7];
    const float* bias = (const float*)d_in[8];
    const int*   mask = (const int*)d_in[9];

    float* out  = (float*)d_out;               // (T,B,E) f32
    float* attn = out + (size_t)T_ * B_ * E_;  // (B,H,T,S) f32

    _Float16* qh  = (_Float16*)d_ws;           // (B,H,T,D)
    _Float16* kh  = qh + NH_;                  // (B,H,S,D)
    _Float16* vhT = kh + NH_;                  // (B,H,D,S)
    _Float16* oh  = vhT + NH_;                 // (T,B,E)

    dim3 blk(512);

    proj_gemm<0, false><<<dim3(32, 8), blk, 0, stream>>>(q, Wq, nullptr, qh, SCALE_);
    proj_gemm<0, false><<<dim3(32, 8), blk, 0, stream>>>(k, Wk, nullptr, kh, 1.0f);
    proj_gemm<1, false><<<dim3(32, 8), blk, 0, stream>>>(v, Wv, nullptr, vhT, 1.0f);

    fused_attn<<<dim3(T_ / 32, B_ * H_), blk, 0, stream>>>(
        qh, kh, vhT, bias, mask, attn, oh);

    proj_gemm<2, true><<<dim3(32, 8), blk, 0, stream>>>(oh, Wp, bp, out, 1.0f);
}

// Round 4
// 362.949 us; speedup vs baseline: 2.7723x; 1.2073x over previous
//
#include <hip/hip_runtime.h>
#include <math.h>

// Problem constants
constexpr int T_ = 1024, S_ = 1024, B_ = 4, E_ = 1024, H_ = 16, D_ = 64;
constexpr float SCALE_ = 0.125f;                  // D^-0.5
constexpr size_t NH_ = (size_t)B_ * H_ * T_ * D_; // 4,194,304 elems

typedef _Float16 h8 __attribute__((ext_vector_type(8)));
typedef _Float16 h4 __attribute__((ext_vector_type(4)));
typedef float f4 __attribute__((ext_vector_type(4)));

__device__ inline f4 mfma16(h8 a, h8 b, f4 c) {
    return __builtin_amdgcn_mfma_f32_16x16x32_f16(a, b, c, 0, 0, 0);
}

// ---------------------------------------------------------------------------
// Projection GEMM via MFMA f16: C = A(M=4096,K=1024) @ W(N=1024,K)^T
//   MODE 0: qh/kh (B,H,T,D) f16, *scale     MODE 1: vhT (B,H,D,S) f16
//   MODE 2: out (M,N) f32 + bias
// 128x128 tile, BK=64, 512 thr = 8 waves (2x4), wave tile 64x32.
// ---------------------------------------------------------------------------
template <int MODE, bool AHALF>
__global__ __launch_bounds__(512) void proj_gemm(
    const void* __restrict__ Av, const float* __restrict__ W,
    const float* __restrict__ bias, void* __restrict__ Cv, float scale)
{
    __shared__ _Float16 As[128][72];   // +8 pad
    __shared__ _Float16 Bs[128][72];

    const int m0 = blockIdx.x * 128, n0 = blockIdx.y * 128;
    const int tid = threadIdx.x;
    const int w = tid >> 6, l = tid & 63, lr = l & 15, lg = l >> 4;
    const int wr = w >> 2, wc = w & 3;

    f4 acc[4][2];
#pragma unroll
    for (int mi = 0; mi < 4; ++mi)
#pragma unroll
        for (int ni = 0; ni < 2; ++ni) acc[mi][ni] = (f4){0.f, 0.f, 0.f, 0.f};

    const float* Af = (const float*)Av;
    const _Float16* Ah = (const _Float16*)Av;

    for (int k0 = 0; k0 < 1024; k0 += 64) {
#pragma unroll
        for (int i = 0; i < 2; ++i) {
            int f = tid + i * 512;
            int row = f >> 3, c = f & 7;
            if (AHALF) {
                *(h8*)&As[row][c * 8] =
                    *(const h8*)&Ah[(size_t)(m0 + row) * 1024 + k0 + c * 8];
            } else {
                const float* p = &Af[(size_t)(m0 + row) * 1024 + k0 + c * 8];
                float4 x0 = *(const float4*)p;
                float4 x1 = *(const float4*)(p + 4);
                h8 va;
                va[0] = (_Float16)x0.x; va[1] = (_Float16)x0.y;
                va[2] = (_Float16)x0.z; va[3] = (_Float16)x0.w;
                va[4] = (_Float16)x1.x; va[5] = (_Float16)x1.y;
                va[6] = (_Float16)x1.z; va[7] = (_Float16)x1.w;
                *(h8*)&As[row][c * 8] = va;
            }
            const float* pw = &W[(size_t)(n0 + row) * 1024 + k0 + c * 8];
            float4 y0 = *(const float4*)pw;
            float4 y1 = *(const float4*)(pw + 4);
            h8 vb;
            vb[0] = (_Float16)y0.x; vb[1] = (_Float16)y0.y;
            vb[2] = (_Float16)y0.z; vb[3] = (_Float16)y0.w;
            vb[4] = (_Float16)y1.x; vb[5] = (_Float16)y1.y;
            vb[6] = (_Float16)y1.z; vb[7] = (_Float16)y1.w;
            *(h8*)&Bs[row][c * 8] = vb;
        }
        __syncthreads();
#pragma unroll
        for (int kk = 0; kk < 2; ++kk) {
            h8 af[4], bf[2];
#pragma unroll
            for (int mi = 0; mi < 4; ++mi)
                af[mi] = *(const h8*)&As[wr * 64 + mi * 16 + lr][kk * 32 + lg * 8];
#pragma unroll
            for (int ni = 0; ni < 2; ++ni)
                bf[ni] = *(const h8*)&Bs[wc * 32 + ni * 16 + lr][kk * 32 + lg * 8];
#pragma unroll
            for (int mi = 0; mi < 4; ++mi)
#pragma unroll
                for (int ni = 0; ni < 2; ++ni)
                    acc[mi][ni] = mfma16(af[mi], bf[ni], acc[mi][ni]);
        }
        __syncthreads();
    }

#pragma unroll
    for (int mi = 0; mi < 4; ++mi)
#pragma unroll
        for (int ni = 0; ni < 2; ++ni)
#pragma unroll
            for (int r = 0; r < 4; ++r) {
                int row = m0 + wr * 64 + mi * 16 + lg * 4 + r;
                int col = n0 + wc * 32 + ni * 16 + lr;
                float vv = acc[mi][ni][r] * scale;
                if (MODE == 0) {
                    int t = row >> 2, b = row & 3, h = col >> 6, d = col & 63;
                    ((_Float16*)Cv)[(((size_t)b * H_ + h) * T_ + t) * D_ + d] = (_Float16)vv;
                } else if (MODE == 1) {
                    int s = row >> 2, b = row & 3, h = col >> 6, d = col & 63;
                    ((_Float16*)Cv)[(((size_t)b * H_ + h) * D_ + d) * S_ + s] = (_Float16)vv;
                } else {
                    ((float*)Cv)[(size_t)row * E_ + col] = vv + bias[col];
                }
            }
}

// ---------------------------------------------------------------------------
// Fused attention: per (bh, 32-row t-tile):
//   phase 1: P = exp(K·Q^T + bias^T) masked (swapped MFMA: col=t, row=s),
//            stored unnormalized f16 in swizzled LDS; per-row sums.
//   phase 2: attn = P * inv  (f32, coalesced: 4 rows x 256B per instruction)
//   phase 3: O = (P @ V) * inv via MFMA, written to oh (T,B,E) f16.
// 512 thr = 8 waves. LDS: 64KB P + 4KB mask.
// Grid: 1D 2048, XCD-swizzled so each XCD owns 8 complete (b,h) groups
// (K/V then hit that XCD's L2 instead of being re-fetched 8x).
// ---------------------------------------------------------------------------
__global__ __launch_bounds__(512) void fused_attn(
    const _Float16* __restrict__ qh, const _Float16* __restrict__ kh,
    const _Float16* __restrict__ vhT, const float* __restrict__ bias,
    const int* __restrict__ mask, float* __restrict__ attn,
    _Float16* __restrict__ oh)
{
    __shared__ _Float16 Pf[32 * 1024];   // swizzled
    __shared__ int smask[S_];
    __shared__ float wsum[8][32];
    __shared__ float sinv[32];
    char* Pb = (char*)Pf;

    // XCD-aware swizzle: vid = (bid%8)*256 + bid/8; 2048 % 8 == 0 (bijective)
    const int bid = blockIdx.x;
    const int vid = (bid & 7) * 256 + (bid >> 3);
    const int bh = vid >> 5;              // 0..63
    const int t0 = (vid & 31) * 32;       // 0..992
    const int b = bh >> 4, h = bh & 15;
    const int tid = threadIdx.x;
    const int w = tid >> 6, l = tid & 63, lr = l & 15, lg = l >> 4;

    for (int i = tid; i < S_; i += 512) smask[i] = mask[(size_t)b * S_ + i];

    // Q fragments (B-operand): rows t = f*16+lr, elems k
    const _Float16* qbase = qh + ((size_t)bh * T_ + t0) * D_;
    h8 qf[2][2];
#pragma unroll
    for (int f = 0; f < 2; ++f)
#pragma unroll
        for (int kk = 0; kk < 2; ++kk)
            qf[f][kk] = *(const h8*)&qbase[(size_t)(f * 16 + lr) * D_ + kk * 32 + lg * 8];

    __syncthreads();

    const _Float16* kbase = kh + (size_t)bh * S_ * D_;
    const float* bbase = bias + ((size_t)bh * T_ + t0) * S_;
    const int wbase = w * 128;          // this wave's s-stripe

    float rs0 = 0.f, rs1 = 0.f;
#pragma unroll
    for (int sub = 0; sub < 8; ++sub) {
        int s0 = wbase + sub * 16;
        h8 kf0 = *(const h8*)&kbase[(size_t)(s0 + lr) * D_ + lg * 8];
        h8 kf1 = *(const h8*)&kbase[(size_t)(s0 + lr) * D_ + 32 + lg * 8];
        int4 mv = *(const int4*)&smask[s0 + lg * 4];
#pragma unroll
        for (int f = 0; f < 2; ++f) {
            f4 c = (f4){0.f, 0.f, 0.f, 0.f};
            c = mfma16(kf0, qf[f][0], c);
            c = mfma16(kf1, qf[f][1], c);
            int t = f * 16 + lr;        // col = t, rows = s0+lg*4+r
            float4 bv = *(const float4*)&bbase[(size_t)t * S_ + s0 + lg * 4];
            float e0 = mv.x ? 0.f : __expf(c[0] + bv.x);
            float e1 = mv.y ? 0.f : __expf(c[1] + bv.y);
            float e2 = mv.z ? 0.f : __expf(c[2] + bv.z);
            float e3 = mv.w ? 0.f : __expf(c[3] + bv.w);
            if (f == 0) rs0 += (e0 + e1) + (e2 + e3);
            else        rs1 += (e0 + e1) + (e2 + e3);
            h4 pv;
            pv[0] = (_Float16)e0; pv[1] = (_Float16)e1;
            pv[2] = (_Float16)e2; pv[3] = (_Float16)e3;
            int off = (t * 2048 + (s0 + lg * 4) * 2) ^ ((t & 7) << 4);
            *(h4*)(Pb + off) = pv;
        }
    }
    // reduce partial sums across lg (lane bits 4,5)
    rs0 += __shfl_xor(rs0, 16); rs0 += __shfl_xor(rs0, 32);
    rs1 += __shfl_xor(rs1, 16); rs1 += __shfl_xor(rs1, 32);
    if (l < 16) { wsum[w][lr] = rs0; wsum[w][16 + lr] = rs1; }
    __syncthreads();
    if (tid < 32) {
        float s = 0.f;
#pragma unroll
        for (int ww = 0; ww < 8; ++ww) s += wsum[ww][tid];
        sinv[tid] = 1.0f / s;
    }
    __syncthreads();

    // ---- normalized attn write, fully coalesced:
    //      thread (rr = tid>>4, c = tid&15) writes float4 at col c*4 + j*64;
    //      per instruction a wave covers 4 rows x 256B contiguous. ----
    {
        int rr = tid >> 4;          // 0..31
        int c  = tid & 15;          // 0..15
        float inv = sinv[rr];
        float* arow = attn + ((size_t)bh * T_ + t0 + rr) * S_;
#pragma unroll
        for (int j = 0; j < 16; ++j) {
            int off = (rr * 2048 + c * 8 + j * 128) ^ ((rr & 7) << 4);
            h4 p = *(const h4*)(Pb + off);
            float4 o = {(float)p[0] * inv, (float)p[1] * inv,
                        (float)p[2] * inv, (float)p[3] * inv};
            *(float4*)&arow[c * 4 + j * 64] = o;
        }
    }

    // ---- PV: wave = 16t x 16d tile; O row t scaled by inv ----
    {
        const int tw = (w & 1) * 16, dbase = (w >> 1) * 16;
        const _Float16* vbase = vhT + (size_t)bh * D_ * S_;
        f4 acc = (f4){0.f, 0.f, 0.f, 0.f};
#pragma unroll 4
        for (int kc = 0; kc < 32; ++kc) {
            int t = tw + lr;
            int off = (t * 2048 + (kc * 32 + lg * 8) * 2) ^ ((t & 7) << 4);
            h8 pf = *(const h8*)(Pb + off);
            h8 vf = *(const h8*)&vbase[(size_t)(dbase + lr) * S_ + kc * 32 + lg * 8];
            acc = mfma16(pf, vf, acc);
        }
#pragma unroll
        for (int r = 0; r < 4; ++r) {
            int t = tw + lg * 4 + r;
            float inv = sinv[t];
            oh[((size_t)(t0 + t) * B_ + b) * E_ + h * 64 + dbase + lr] =
                (_Float16)(acc[r] * inv);
        }
    }
}

// ---------------------------------------------------------------------------
extern "C" void kernel_launch(void* const* d_in, const int* in_sizes, int n_in,
                              void* d_out, int out_size, void* d_ws, size_t ws_size,
                              hipStream_t stream)
{
    const float* q    = (const float*)d_in[0];
    const float* k    = (const float*)d_in[1];
    const float* v    = (const float*)d_in[2];
    const float* Wq   = (const float*)d_in[3];
    const float* Wk   = (const float*)d_in[4];
    const float* Wv   = (const float*)d_in[5];
    const float* Wp   = (const float*)d_in[6];
    const float* bp   = (const float*)d_in[7];
    const float* bias = (const float*)d_in[8];
    const int*   mask = (const int*)d_in[9];

    float* out  = (float*)d_out;               // (T,B,E) f32
    float* attn = out + (size_t)T_ * B_ * E_;  // (B,H,T,S) f32

    _Float16* qh  = (_Float16*)d_ws;           // (B,H,T,D)
    _Float16* kh  = qh + NH_;                  // (B,H,S,D)
    _Float16* vhT = kh + NH_;                  // (B,H,D,S)
    _Float16* oh  = vhT + NH_;                 // (T,B,E)

    dim3 blk(512);

    proj_gemm<0, false><<<dim3(32, 8), blk, 0, stream>>>(q, Wq, nullptr, qh, SCALE_);
    proj_gemm<0, false><<<dim3(32, 8), blk, 0, stream>>>(k, Wk, nullptr, kh, 1.0f);
    proj_gemm<1, false><<<dim3(32, 8), blk, 0, stream>>>(v, Wv, nullptr, vhT, 1.0f);

    fused_attn<<<dim3(2048), blk, 0, stream>>>(qh, kh, vhT, bias, mask, attn, oh);

    proj_gemm<2, true><<<dim3(32, 8), blk, 0, stream>>>(oh, Wp, bp, out, 1.0f);
}

// Round 5
// 330.453 us; speedup vs baseline: 3.0449x; 1.0983x over previous
//
#include <hip/hip_runtime.h>
#include <math.h>

// Problem constants
constexpr int T_ = 1024, S_ = 1024, B_ = 4, E_ = 1024, H_ = 16, D_ = 64;
constexpr float SCALE_ = 0.125f;                  // D^-0.5
constexpr size_t NH_ = (size_t)B_ * H_ * T_ * D_; // 4,194,304 elems

typedef _Float16 h8 __attribute__((ext_vector_type(8)));
typedef _Float16 h4 __attribute__((ext_vector_type(4)));
typedef float f4 __attribute__((ext_vector_type(4)));

__device__ inline f4 mfma16(h8 a, h8 b, f4 c) {
    return __builtin_amdgcn_mfma_f32_16x16x32_f16(a, b, c, 0, 0, 0);
}

// ---------------------------------------------------------------------------
// f32 -> f16 elementwise converter (8 elems/thread)
// ---------------------------------------------------------------------------
__global__ __launch_bounds__(256) void cvt_f16(
    const float* __restrict__ in, _Float16* __restrict__ out, int n8)
{
    int i = blockIdx.x * 256 + threadIdx.x;
    if (i >= n8) return;
    const float* p = in + (size_t)i * 8;
    float4 a = *(const float4*)p;
    float4 b = *(const float4*)(p + 4);
    h8 v;
    v[0] = (_Float16)a.x; v[1] = (_Float16)a.y;
    v[2] = (_Float16)a.z; v[3] = (_Float16)a.w;
    v[4] = (_Float16)b.x; v[5] = (_Float16)b.y;
    v[6] = (_Float16)b.z; v[7] = (_Float16)b.w;
    *(h8*)&out[(size_t)i * 8] = v;
}

// ---------------------------------------------------------------------------
// Projection GEMM via MFMA f16 (A and W already f16):
//   C = A(M=4096,K=1024) @ W(N=1024,K)^T
//   MODE 0: qh/kh (B,H,T,D) f16, *scale     MODE 1: vhT (B,H,D,S) f16
//   MODE 2: out (M,N) f32 + bias
// 128x128 tile, BK=64, 512 thr = 8 waves (2x4), wave tile 64x32.
// ---------------------------------------------------------------------------
template <int MODE>
__global__ __launch_bounds__(512) void proj_gemm(
    const _Float16* __restrict__ A, const _Float16* __restrict__ W,
    const float* __restrict__ bias, void* __restrict__ Cv, float scale)
{
    __shared__ _Float16 As[128][72];   // +8 pad
    __shared__ _Float16 Bs[128][72];

    const int m0 = blockIdx.x * 128, n0 = blockIdx.y * 128;
    const int tid = threadIdx.x;
    const int w = tid >> 6, l = tid & 63, lr = l & 15, lg = l >> 4;
    const int wr = w >> 2, wc = w & 3;

    f4 acc[4][2];
#pragma unroll
    for (int mi = 0; mi < 4; ++mi)
#pragma unroll
        for (int ni = 0; ni < 2; ++ni) acc[mi][ni] = (f4){0.f, 0.f, 0.f, 0.f};

    for (int k0 = 0; k0 < 1024; k0 += 64) {
#pragma unroll
        for (int i = 0; i < 2; ++i) {
            int f = tid + i * 512;
            int row = f >> 3, c = f & 7;
            *(h8*)&As[row][c * 8] = *(const h8*)&A[(size_t)(m0 + row) * 1024 + k0 + c * 8];
            *(h8*)&Bs[row][c * 8] = *(const h8*)&W[(size_t)(n0 + row) * 1024 + k0 + c * 8];
        }
        __syncthreads();
#pragma unroll
        for (int kk = 0; kk < 2; ++kk) {
            h8 af[4], bf[2];
#pragma unroll
            for (int mi = 0; mi < 4; ++mi)
                af[mi] = *(const h8*)&As[wr * 64 + mi * 16 + lr][kk * 32 + lg * 8];
#pragma unroll
            for (int ni = 0; ni < 2; ++ni)
                bf[ni] = *(const h8*)&Bs[wc * 32 + ni * 16 + lr][kk * 32 + lg * 8];
#pragma unroll
            for (int mi = 0; mi < 4; ++mi)
#pragma unroll
                for (int ni = 0; ni < 2; ++ni)
                    acc[mi][ni] = mfma16(af[mi], bf[ni], acc[mi][ni]);
        }
        __syncthreads();
    }

#pragma unroll
    for (int mi = 0; mi < 4; ++mi)
#pragma unroll
        for (int ni = 0; ni < 2; ++ni)
#pragma unroll
            for (int r = 0; r < 4; ++r) {
                int row = m0 + wr * 64 + mi * 16 + lg * 4 + r;
                int col = n0 + wc * 32 + ni * 16 + lr;
                float vv = acc[mi][ni][r] * scale;
                if (MODE == 0) {
                    int t = row >> 2, b = row & 3, h = col >> 6, d = col & 63;
                    ((_Float16*)Cv)[(((size_t)b * H_ + h) * T_ + t) * D_ + d] = (_Float16)vv;
                } else if (MODE == 1) {
                    int s = row >> 2, b = row & 3, h = col >> 6, d = col & 63;
                    ((_Float16*)Cv)[(((size_t)b * H_ + h) * D_ + d) * S_ + s] = (_Float16)vv;
                } else {
                    ((float*)Cv)[(size_t)row * E_ + col] = vv + bias[col];
                }
            }
}

// ---------------------------------------------------------------------------
// Fused attention, per (bh, 32-row t-tile), 512 thr = 8 waves:
//   ph1 : expS = exp(K·Q^T) (swapped MFMA, col=t row=s) -> swizzled LDS f16.
//         No bias here (exp(a+b)=exp(a)exp(b)) -> no scattered bias reads.
//   ph2a: coalesced row pass: P = mask ? 0 : expS * exp(bias)  (bias read in
//         4x256B segments), rowsum via 16-lane shfl, P back to LDS.
//   ph2b: attn = P * inv (f32, coalesced 256B stores)
//   ph3 : O = (P @ V) * inv via MFMA -> oh (T,B,E) f16.
// Grid: 1D 2048, XCD-swizzled (each XCD owns 8 complete (b,h) groups).
// ---------------------------------------------------------------------------
__global__ __launch_bounds__(512) void fused_attn(
    const _Float16* __restrict__ qh, const _Float16* __restrict__ kh,
    const _Float16* __restrict__ vhT, const float* __restrict__ bias,
    const int* __restrict__ mask, float* __restrict__ attn,
    _Float16* __restrict__ oh)
{
    __shared__ _Float16 Pf[32 * 1024];   // swizzled
    __shared__ int smask[S_];
    __shared__ float sinv[32];
    char* Pb = (char*)Pf;

    const int bid = blockIdx.x;
    const int vid = (bid & 7) * 256 + (bid >> 3);
    const int bh = vid >> 5;              // 0..63
    const int t0 = (vid & 31) * 32;       // 0..992
    const int b = bh >> 4, h = bh & 15;
    const int tid = threadIdx.x;
    const int w = tid >> 6, l = tid & 63, lr = l & 15, lg = l >> 4;

    for (int i = tid; i < S_; i += 512) smask[i] = mask[(size_t)b * S_ + i];

    // Q fragments (B-operand): rows t = f*16+lr, elems k
    const _Float16* qbase = qh + ((size_t)bh * T_ + t0) * D_;
    h8 qf[2][2];
#pragma unroll
    for (int f = 0; f < 2; ++f)
#pragma unroll
        for (int kk = 0; kk < 2; ++kk)
            qf[f][kk] = *(const h8*)&qbase[(size_t)(f * 16 + lr) * D_ + kk * 32 + lg * 8];

    __syncthreads();

    const _Float16* kbase = kh + (size_t)bh * S_ * D_;
    const int wbase = w * 128;          // this wave's s-stripe

    // ---- phase 1: expS = exp(qk) into LDS (MFMA layout, swizzled) ----
#pragma unroll
    for (int sub = 0; sub < 8; ++sub) {
        int s0 = wbase + sub * 16;
        h8 kf0 = *(const h8*)&kbase[(size_t)(s0 + lr) * D_ + lg * 8];
        h8 kf1 = *(const h8*)&kbase[(size_t)(s0 + lr) * D_ + 32 + lg * 8];
#pragma unroll
        for (int f = 0; f < 2; ++f) {
            f4 c = (f4){0.f, 0.f, 0.f, 0.f};
            c = mfma16(kf0, qf[f][0], c);
            c = mfma16(kf1, qf[f][1], c);
            int t = f * 16 + lr;        // col = t, rows = s0+lg*4+r
            h4 pv;
            pv[0] = (_Float16)__expf(c[0]);
            pv[1] = (_Float16)__expf(c[1]);
            pv[2] = (_Float16)__expf(c[2]);
            pv[3] = (_Float16)__expf(c[3]);
            int off = (t * 2048 + (s0 + lg * 4) * 2) ^ ((t & 7) << 4);
            *(h4*)(Pb + off) = pv;
        }
    }
    __syncthreads();

    // ---- phase 2a: coalesced bias pass: P = mask?0:expS*exp(bias); rowsum.
    {
        int rr = tid >> 4;          // 0..31  (row)
        int c  = tid & 15;          // 0..15  (col group)
        const float* brow = bias + ((size_t)bh * T_ + t0 + rr) * S_;
        float rs = 0.f;
#pragma unroll
        for (int j = 0; j < 16; ++j) {
            int col = c * 4 + j * 64;
            int off = (rr * 2048 + col * 2) ^ ((rr & 7) << 4);
            h4 p = *(const h4*)(Pb + off);
            float4 bv = *(const float4*)&brow[col];
            int4 mv = *(const int4*)&smask[col];
            float p0 = mv.x ? 0.f : (float)p[0] * __expf(bv.x);
            float p1 = mv.y ? 0.f : (float)p[1] * __expf(bv.y);
            float p2 = mv.z ? 0.f : (float)p[2] * __expf(bv.z);
            float p3 = mv.w ? 0.f : (float)p[3] * __expf(bv.w);
            rs += (p0 + p1) + (p2 + p3);
            h4 pn;
            pn[0] = (_Float16)p0; pn[1] = (_Float16)p1;
            pn[2] = (_Float16)p2; pn[3] = (_Float16)p3;
            *(h4*)(Pb + off) = pn;
        }
        rs += __shfl_xor(rs, 1); rs += __shfl_xor(rs, 2);
        rs += __shfl_xor(rs, 4); rs += __shfl_xor(rs, 8);
        if (c == 0) sinv[rr] = 1.0f / rs;
    }
    __syncthreads();

    // ---- phase 2b: attn write (f32, 4 rows x 256B per instruction) ----
    {
        int rr = tid >> 4;
        int c  = tid & 15;
        float inv = sinv[rr];
        float* arow = attn + ((size_t)bh * T_ + t0 + rr) * S_;
#pragma unroll
        for (int j = 0; j < 16; ++j) {
            int col = c * 4 + j * 64;
            int off = (rr * 2048 + col * 2) ^ ((rr & 7) << 4);
            h4 p = *(const h4*)(Pb + off);
            float4 o = {(float)p[0] * inv, (float)p[1] * inv,
                        (float)p[2] * inv, (float)p[3] * inv};
            *(float4*)&arow[col] = o;
        }
    }

    // ---- phase 3: PV: wave = 16t x 16d tile; O row t scaled by inv ----
    {
        const int tw = (w & 1) * 16, dbase = (w >> 1) * 16;
        const _Float16* vbase = vhT + (size_t)bh * D_ * S_;
        f4 acc = (f4){0.f, 0.f, 0.f, 0.f};
#pragma unroll 4
        for (int kc = 0; kc < 32; ++kc) {
            int t = tw + lr;
            int off = (t * 2048 + (kc * 32 + lg * 8) * 2) ^ ((t & 7) << 4);
            h8 pf = *(const h8*)(Pb + off);
            h8 vf = *(const h8*)&vbase[(size_t)(dbase + lr) * S_ + kc * 32 + lg * 8];
            acc = mfma16(pf, vf, acc);
        }
#pragma unroll
        for (int r = 0; r < 4; ++r) {
            int t = tw + lg * 4 + r;
            float inv = sinv[t];
            oh[((size_t)(t0 + t) * B_ + b) * E_ + h * 64 + dbase + lr] =
                (_Float16)(acc[r] * inv);
        }
    }
}

// ---------------------------------------------------------------------------
extern "C" void kernel_launch(void* const* d_in, const int* in_sizes, int n_in,
                              void* d_out, int out_size, void* d_ws, size_t ws_size,
                              hipStream_t stream)
{
    const float* q    = (const float*)d_in[0];
    const float* k    = (const float*)d_in[1];
    const float* v    = (const float*)d_in[2];
    const float* Wq   = (const float*)d_in[3];
    const float* Wk   = (const float*)d_in[4];
    const float* Wv   = (const float*)d_in[5];
    const float* Wp   = (const float*)d_in[6];
    const float* bp   = (const float*)d_in[7];
    const float* bias = (const float*)d_in[8];
    const int*   mask = (const int*)d_in[9];

    float* out  = (float*)d_out;               // (T,B,E) f32
    float* attn = out + (size_t)T_ * B_ * E_;  // (B,H,T,S) f32

    _Float16* qh   = (_Float16*)d_ws;          // (B,H,T,D)
    _Float16* kh   = qh + NH_;                 // (B,H,S,D)
    _Float16* vhT  = kh + NH_;                 // (B,H,D,S)
    _Float16* oh   = vhT + NH_;                // (T,B,E)
    _Float16* q16  = oh + NH_;                 // (T,B,E) f16
    _Float16* k16  = q16 + NH_;
    _Float16* v16  = k16 + NH_;
    _Float16* Wq16 = v16 + NH_;                // (E,E) f16
    _Float16* Wk16 = Wq16 + (size_t)E_ * E_;
    _Float16* Wv16 = Wk16 + (size_t)E_ * E_;
    _Float16* Wp16 = Wv16 + (size_t)E_ * E_;

    dim3 blk(512);

    // f32 -> f16 conversions (activations + weights)
    constexpr int NBIG = (int)(NH_ / 8);             // 524288 -> 2048 blocks
    constexpr int NW   = (int)((size_t)E_ * E_ / 8); // 131072 -> 512 blocks
    cvt_f16<<<dim3(NBIG / 256), dim3(256), 0, stream>>>(q, q16, NBIG);
    cvt_f16<<<dim3(NBIG / 256), dim3(256), 0, stream>>>(k, k16, NBIG);
    cvt_f16<<<dim3(NBIG / 256), dim3(256), 0, stream>>>(v, v16, NBIG);
    cvt_f16<<<dim3(NW / 256), dim3(256), 0, stream>>>(Wq, Wq16, NW);
    cvt_f16<<<dim3(NW / 256), dim3(256), 0, stream>>>(Wk, Wk16, NW);
    cvt_f16<<<dim3(NW / 256), dim3(256), 0, stream>>>(Wv, Wv16, NW);
    cvt_f16<<<dim3(NW / 256), dim3(256), 0, stream>>>(Wp, Wp16, NW);

    proj_gemm<0><<<dim3(32, 8), blk, 0, stream>>>(q16, Wq16, nullptr, qh, SCALE_);
    proj_gemm<0><<<dim3(32, 8), blk, 0, stream>>>(k16, Wk16, nullptr, kh, 1.0f);
    proj_gemm<1><<<dim3(32, 8), blk, 0, stream>>>(v16, Wv16, nullptr, vhT, 1.0f);

    fused_attn<<<dim3(2048), blk, 0, stream>>>(qh, kh, vhT, bias, mask, attn, oh);

    proj_gemm<2><<<dim3(32, 8), blk, 0, stream>>>(oh, Wp16, bp, out, 1.0f);
}

// Round 6
// 330.035 us; speedup vs baseline: 3.0488x; 1.0013x over previous
//
#include <hip/hip_runtime.h>
#include <math.h>

// Problem constants
constexpr int T_ = 1024, S_ = 1024, B_ = 4, E_ = 1024, H_ = 16, D_ = 64;
constexpr float SCALE_ = 0.125f;                  // D^-0.5
constexpr size_t NH_ = (size_t)B_ * H_ * T_ * D_; // 4,194,304 elems
constexpr size_t EE_ = (size_t)E_ * E_;           // 1,048,576 elems

typedef _Float16 h8 __attribute__((ext_vector_type(8)));
typedef _Float16 h4 __attribute__((ext_vector_type(4)));
typedef float f4 __attribute__((ext_vector_type(4)));

__device__ inline f4 mfma16(h8 a, h8 b, f4 c) {
    return __builtin_amdgcn_mfma_f32_16x16x32_f16(a, b, c, 0, 0, 0);
}

// ---------------------------------------------------------------------------
// Fused f32 -> f16 converter for all 7 tensors (outputs contiguous in ws).
// ---------------------------------------------------------------------------
__global__ __launch_bounds__(256) void cvt_all(
    const float* __restrict__ q, const float* __restrict__ k,
    const float* __restrict__ v, const float* __restrict__ wq,
    const float* __restrict__ wk, const float* __restrict__ wv,
    const float* __restrict__ wp, _Float16* __restrict__ dst)
{
    const int i8 = blockIdx.x * 256 + threadIdx.x;   // 0 .. 2097151
    constexpr int BIG = (int)(NH_ / 8);              // 524288
    constexpr int WSZ = (int)(EE_ / 8);              // 131072
    const float* src;
    int loc;
    if (i8 < 3 * BIG) {
        int t = i8 / BIG; loc = i8 - t * BIG;
        src = t == 0 ? q : (t == 1 ? k : v);
    } else {
        int r = i8 - 3 * BIG;
        int t = r / WSZ; loc = r - t * WSZ;
        src = t == 0 ? wq : (t == 1 ? wk : (t == 2 ? wv : wp));
    }
    const float* p = src + (size_t)loc * 8;
    float4 a = *(const float4*)p;
    float4 b = *(const float4*)(p + 4);
    h8 o;
    o[0] = (_Float16)a.x; o[1] = (_Float16)a.y;
    o[2] = (_Float16)a.z; o[3] = (_Float16)a.w;
    o[4] = (_Float16)b.x; o[5] = (_Float16)b.y;
    o[6] = (_Float16)b.z; o[7] = (_Float16)b.w;
    *(h8*)&dst[(size_t)i8 * 8] = o;
}

// ---------------------------------------------------------------------------
// Projection GEMM via MFMA f16 (A and W already f16):
//   C = A(M=4096,K=1024) @ W(N=1024,K)^T
//   MODE 0: qh/kh (B,H,T,D) f16, *scale     MODE 1: vhT (B,H,D,S) f16
//   MODE 2: out (M,N) f32 + bias
// ---------------------------------------------------------------------------
template <int MODE>
__global__ __launch_bounds__(512) void proj_gemm(
    const _Float16* __restrict__ A, const _Float16* __restrict__ W,
    const float* __restrict__ bias, void* __restrict__ Cv, float scale)
{
    __shared__ _Float16 As[128][72];   // +8 pad
    __shared__ _Float16 Bs[128][72];

    const int m0 = blockIdx.x * 128, n0 = blockIdx.y * 128;
    const int tid = threadIdx.x;
    const int w = tid >> 6, l = tid & 63, lr = l & 15, lg = l >> 4;
    const int wr = w >> 2, wc = w & 3;

    f4 acc[4][2];
#pragma unroll
    for (int mi = 0; mi < 4; ++mi)
#pragma unroll
        for (int ni = 0; ni < 2; ++ni) acc[mi][ni] = (f4){0.f, 0.f, 0.f, 0.f};

    for (int k0 = 0; k0 < 1024; k0 += 64) {
#pragma unroll
        for (int i = 0; i < 2; ++i) {
            int f = tid + i * 512;
            int row = f >> 3, c = f & 7;
            *(h8*)&As[row][c * 8] = *(const h8*)&A[(size_t)(m0 + row) * 1024 + k0 + c * 8];
            *(h8*)&Bs[row][c * 8] = *(const h8*)&W[(size_t)(n0 + row) * 1024 + k0 + c * 8];
        }
        __syncthreads();
#pragma unroll
        for (int kk = 0; kk < 2; ++kk) {
            h8 af[4], bf[2];
#pragma unroll
            for (int mi = 0; mi < 4; ++mi)
                af[mi] = *(const h8*)&As[wr * 64 + mi * 16 + lr][kk * 32 + lg * 8];
#pragma unroll
            for (int ni = 0; ni < 2; ++ni)
                bf[ni] = *(const h8*)&Bs[wc * 32 + ni * 16 + lr][kk * 32 + lg * 8];
#pragma unroll
            for (int mi = 0; mi < 4; ++mi)
#pragma unroll
                for (int ni = 0; ni < 2; ++ni)
                    acc[mi][ni] = mfma16(af[mi], bf[ni], acc[mi][ni]);
        }
        __syncthreads();
    }

#pragma unroll
    for (int mi = 0; mi < 4; ++mi)
#pragma unroll
        for (int ni = 0; ni < 2; ++ni)
#pragma unroll
            for (int r = 0; r < 4; ++r) {
                int row = m0 + wr * 64 + mi * 16 + lg * 4 + r;
                int col = n0 + wc * 32 + ni * 16 + lr;
                float vv = acc[mi][ni][r] * scale;
                if (MODE == 0) {
                    int t = row >> 2, b = row & 3, h = col >> 6, d = col & 63;
                    ((_Float16*)Cv)[(((size_t)b * H_ + h) * T_ + t) * D_ + d] = (_Float16)vv;
                } else if (MODE == 1) {
                    int s = row >> 2, b = row & 3, h = col >> 6, d = col & 63;
                    ((_Float16*)Cv)[(((size_t)b * H_ + h) * D_ + d) * S_ + s] = (_Float16)vv;
                } else {
                    ((float*)Cv)[(size_t)row * E_ + col] = vv + bias[col];
                }
            }
}

// ---------------------------------------------------------------------------
// Fused attention, per (bh, 16-row t-tile), 512 thr = 8 waves.
// LDS: P 32KB + aux 4KB (mask, later PV-reduce) + sinv 64B -> ~37KB,
// 4 blocks/CU (vs 2 before) for latency hiding.
//   ph1 : expS = exp(K.Q^T) (swapped MFMA) -> swizzled LDS f16
//   ph2 : coalesced: P = mask?0:expS*exp(bias); rowsum wave-local (32-lane
//         shfl); P kept in regs; attn = P*inv streamed straight out.
//   ph3 : O = (P @ V)*inv, wave pairs split S, 4KB LDS reduce.
// Grid: 1D 4096, XCD-swizzled (each XCD owns 8 complete (b,h) groups).
// ---------------------------------------------------------------------------
__global__ __launch_bounds__(512, 8) void fused_attn(
    const _Float16* __restrict__ qh, const _Float16* __restrict__ kh,
    const _Float16* __restrict__ vhT, const float* __restrict__ bias,
    const int* __restrict__ mask, float* __restrict__ attn,
    _Float16* __restrict__ oh)
{
    __shared__ _Float16 Pf[16 * 1024];   // swizzled, 32 KB
    __shared__ int aux_i[1024];          // mask (ph2) / PV partials (ph3)
    __shared__ float sinv16[16];
    char* Pb = (char*)Pf;

    const int bid = blockIdx.x;
    const int vid = (bid & 7) * 512 + (bid >> 3);   // 4096 % 8 == 0, bijective
    const int bh = vid >> 6;              // 0..63
    const int t0 = (vid & 63) * 16;       // 0..1008
    const int b = bh >> 4, h = bh & 15;
    const int tid = threadIdx.x;
    const int w = tid >> 6, l = tid & 63, lr = l & 15, lg = l >> 4;

    for (int i = tid; i < S_; i += 512) aux_i[i] = mask[(size_t)b * S_ + i];

    // Q fragments (B-operand): col t = lr, elems k
    const _Float16* qbase = qh + ((size_t)bh * T_ + t0) * D_;
    h8 qf0 = *(const h8*)&qbase[(size_t)lr * D_ + lg * 8];
    h8 qf1 = *(const h8*)&qbase[(size_t)lr * D_ + 32 + lg * 8];

    const _Float16* kbase = kh + (size_t)bh * S_ * D_;
    const int wbase = w * 128;            // this wave's s-stripe

    // ---- phase 1: expS = exp(qk) into LDS (MFMA layout, swizzled) ----
#pragma unroll
    for (int sub = 0; sub < 8; ++sub) {
        int s0 = wbase + sub * 16;
        h8 kf0 = *(const h8*)&kbase[(size_t)(s0 + lr) * D_ + lg * 8];
        h8 kf1 = *(const h8*)&kbase[(size_t)(s0 + lr) * D_ + 32 + lg * 8];
        f4 c = (f4){0.f, 0.f, 0.f, 0.f};
        c = mfma16(kf0, qf0, c);
        c = mfma16(kf1, qf1, c);
        h4 pv;
        pv[0] = (_Float16)__expf(c[0]);
        pv[1] = (_Float16)__expf(c[1]);
        pv[2] = (_Float16)__expf(c[2]);
        pv[3] = (_Float16)__expf(c[3]);
        int off = (lr * 2048 + (s0 + lg * 4) * 2) ^ ((lr & 7) << 4);
        *(h4*)(Pb + off) = pv;
    }
    __syncthreads();

    // ---- phase 2: P = mask?0:expS*exp(bias); wave-local rowsum; attn out.
    {
        const int rr = tid >> 5;          // 0..15 (row); wave owns 2 rows
        const int c  = tid & 31;          // 0..31 (col group)
        const float* brow = bias + ((size_t)bh * T_ + t0 + rr) * S_;
        h4 pns[8];
        float rs = 0.f;
#pragma unroll
        for (int j = 0; j < 8; ++j) {
            int col = c * 4 + j * 128;
            int off = (rr * 2048 + col * 2) ^ ((rr & 7) << 4);
            h4 p = *(const h4*)(Pb + off);
            float4 bv = *(const float4*)&brow[col];
            int4 mv = *(const int4*)&aux_i[col];
            float p0 = mv.x ? 0.f : (float)p[0] * __expf(bv.x);
            float p1 = mv.y ? 0.f : (float)p[1] * __expf(bv.y);
            float p2 = mv.z ? 0.f : (float)p[2] * __expf(bv.z);
            float p3 = mv.w ? 0.f : (float)p[3] * __expf(bv.w);
            rs += (p0 + p1) + (p2 + p3);
            h4 pn;
            pn[0] = (_Float16)p0; pn[1] = (_Float16)p1;
            pn[2] = (_Float16)p2; pn[3] = (_Float16)p3;
            pns[j] = pn;
            *(h4*)(Pb + off) = pn;
        }
        rs += __shfl_xor(rs, 1); rs += __shfl_xor(rs, 2);
        rs += __shfl_xor(rs, 4); rs += __shfl_xor(rs, 8);
        rs += __shfl_xor(rs, 16);
        float inv = 1.0f / rs;
        if (c == 0) sinv16[rr] = inv;

        float* arow = attn + ((size_t)bh * T_ + t0 + rr) * S_;
#pragma unroll
        for (int j = 0; j < 8; ++j) {
            int col = c * 4 + j * 128;
            h4 p = pns[j];
            float4 o = {(float)p[0] * inv, (float)p[1] * inv,
                        (float)p[2] * inv, (float)p[3] * inv};
            *(float4*)&arow[col] = o;
        }
    }
    __syncthreads();

    // ---- phase 3: PV, wave pairs split S (512 each), LDS reduce ----
    {
        const int sh = w & 1, dbase = (w >> 1) * 16;
        const _Float16* vbase = vhT + (size_t)bh * D_ * S_;
        f4 acc = (f4){0.f, 0.f, 0.f, 0.f};
#pragma unroll 4
        for (int kc = 0; kc < 16; ++kc) {
            int s0 = sh * 512 + kc * 32;
            int off = (lr * 2048 + (s0 + lg * 8) * 2) ^ ((lr & 7) << 4);
            h8 pf = *(const h8*)(Pb + off);
            h8 vf = *(const h8*)&vbase[(size_t)(dbase + lr) * S_ + s0 + lg * 8];
            acc = mfma16(pf, vf, acc);
        }
        float* pvred = (float*)aux_i;     // reuse mask buffer (barrier above)
        if (sh) {
#pragma unroll
            for (int r = 0; r < 4; ++r)
                pvred[(lg * 4 + r) * 64 + dbase + lr] = acc[r];
        }
        __syncthreads();
        if (!sh) {
#pragma unroll
            for (int r = 0; r < 4; ++r) {
                int t = lg * 4 + r;
                float o = (acc[r] + pvred[t * 64 + dbase + lr]) * sinv16[t];
                oh[((size_t)(t0 + t) * B_ + b) * E_ + h * 64 + dbase + lr] = (_Float16)o;
            }
        }
    }
}

// ---------------------------------------------------------------------------
extern "C" void kernel_launch(void* const* d_in, const int* in_sizes, int n_in,
                              void* d_out, int out_size, void* d_ws, size_t ws_size,
                              hipStream_t stream)
{
    const float* q    = (const float*)d_in[0];
    const float* k    = (const float*)d_in[1];
    const float* v    = (const float*)d_in[2];
    const float* Wq   = (const float*)d_in[3];
    const float* Wk   = (const float*)d_in[4];
    const float* Wv   = (const float*)d_in[5];
    const float* Wp   = (const float*)d_in[6];
    const float* bp   = (const float*)d_in[7];
    const float* bias = (const float*)d_in[8];
    const int*   mask = (const int*)d_in[9];

    float* out  = (float*)d_out;               // (T,B,E) f32
    float* attn = out + (size_t)T_ * B_ * E_;  // (B,H,T,S) f32

    _Float16* qh   = (_Float16*)d_ws;          // (B,H,T,D)
    _Float16* kh   = qh + NH_;                 // (B,H,S,D)
    _Float16* vhT  = kh + NH_;                 // (B,H,D,S)
    _Float16* oh   = vhT + NH_;                // (T,B,E)
    _Float16* q16  = oh + NH_;                 // contiguous cvt_all dst:
    _Float16* k16  = q16 + NH_;                //   q16,k16,v16,Wq16..Wp16
    _Float16* v16  = k16 + NH_;
    _Float16* Wq16 = v16 + NH_;
    _Float16* Wk16 = Wq16 + EE_;
    _Float16* Wv16 = Wk16 + EE_;
    _Float16* Wp16 = Wv16 + EE_;

    dim3 blk(512);

    // all f32 -> f16 conversions in one launch (dst = q16 base, contiguous)
    cvt_all<<<dim3(8192), dim3(256), 0, stream>>>(q, k, v, Wq, Wk, Wv, Wp, q16);

    proj_gemm<0><<<dim3(32, 8), blk, 0, stream>>>(q16, Wq16, nullptr, qh, SCALE_);
    proj_gemm<0><<<dim3(32, 8), blk, 0, stream>>>(k16, Wk16, nullptr, kh, 1.0f);
    proj_gemm<1><<<dim3(32, 8), blk, 0, stream>>>(v16, Wv16, nullptr, vhT, 1.0f);

    fused_attn<<<dim3(4096), blk, 0, stream>>>(qh, kh, vhT, bias, mask, attn, oh);

    proj_gemm<2><<<dim3(32, 8), blk, 0, stream>>>(oh, Wp16, bp, out, 1.0f);
}

// Round 7
// 299.343 us; speedup vs baseline: 3.3614x; 1.1025x over previous
//
#include <hip/hip_runtime.h>
#include <math.h>

// Problem constants
constexpr int T_ = 1024, S_ = 1024, B_ = 4, E_ = 1024, H_ = 16, D_ = 64;
constexpr float SCALE_ = 0.125f;                  // D^-0.5
constexpr size_t NH_ = (size_t)B_ * H_ * T_ * D_; // 4,194,304 elems
constexpr size_t EE_ = (size_t)E_ * E_;           // 1,048,576 elems

typedef _Float16 h8 __attribute__((ext_vector_type(8)));
typedef _Float16 h4 __attribute__((ext_vector_type(4)));
typedef float f4 __attribute__((ext_vector_type(4)));

__device__ inline f4 mfma16(h8 a, h8 b, f4 c) {
    return __builtin_amdgcn_mfma_f32_16x16x32_f16(a, b, c, 0, 0, 0);
}

// ---------------------------------------------------------------------------
// Fused f32 -> f16 converter for all 7 tensors (outputs contiguous in ws).
// ---------------------------------------------------------------------------
__global__ __launch_bounds__(256) void cvt_all(
    const float* __restrict__ q, const float* __restrict__ k,
    const float* __restrict__ v, const float* __restrict__ wq,
    const float* __restrict__ wk, const float* __restrict__ wv,
    const float* __restrict__ wp, _Float16* __restrict__ dst)
{
    const int i8 = blockIdx.x * 256 + threadIdx.x;   // 0 .. 2097151
    constexpr int BIG = (int)(NH_ / 8);              // 524288
    constexpr int WSZ = (int)(EE_ / 8);              // 131072
    const float* src;
    int loc;
    if (i8 < 3 * BIG) {
        int t = i8 / BIG; loc = i8 - t * BIG;
        src = t == 0 ? q : (t == 1 ? k : v);
    } else {
        int r = i8 - 3 * BIG;
        int t = r / WSZ; loc = r - t * WSZ;
        src = t == 0 ? wq : (t == 1 ? wk : (t == 2 ? wv : wp));
    }
    const float* p = src + (size_t)loc * 8;
    float4 a = *(const float4*)p;
    float4 b = *(const float4*)(p + 4);
    h8 o;
    o[0] = (_Float16)a.x; o[1] = (_Float16)a.y;
    o[2] = (_Float16)a.z; o[3] = (_Float16)a.w;
    o[4] = (_Float16)b.x; o[5] = (_Float16)b.y;
    o[6] = (_Float16)b.z; o[7] = (_Float16)b.w;
    *(h8*)&dst[(size_t)i8 * 8] = o;
}

// ---------------------------------------------------------------------------
// Projection GEMM via MFMA f16 (A and W already f16):
//   C = A(M=4096,K=1024) @ W(N=1024,K)^T
//   MODE 0: qh/kh (B,H,T,D) f16, *scale     MODE 1: vhT (B,H,D,S) f16
//   MODE 2: out (M,N) f32 + bias
// ---------------------------------------------------------------------------
template <int MODE>
__global__ __launch_bounds__(512) void proj_gemm(
    const _Float16* __restrict__ A, const _Float16* __restrict__ W,
    const float* __restrict__ bias, void* __restrict__ Cv, float scale)
{
    __shared__ _Float16 As[128][72];   // +8 pad
    __shared__ _Float16 Bs[128][72];

    const int m0 = blockIdx.x * 128, n0 = blockIdx.y * 128;
    const int tid = threadIdx.x;
    const int w = tid >> 6, l = tid & 63, lr = l & 15, lg = l >> 4;
    const int wr = w >> 2, wc = w & 3;

    f4 acc[4][2];
#pragma unroll
    for (int mi = 0; mi < 4; ++mi)
#pragma unroll
        for (int ni = 0; ni < 2; ++ni) acc[mi][ni] = (f4){0.f, 0.f, 0.f, 0.f};

    for (int k0 = 0; k0 < 1024; k0 += 64) {
#pragma unroll
        for (int i = 0; i < 2; ++i) {
            int f = tid + i * 512;
            int row = f >> 3, c = f & 7;
            *(h8*)&As[row][c * 8] = *(const h8*)&A[(size_t)(m0 + row) * 1024 + k0 + c * 8];
            *(h8*)&Bs[row][c * 8] = *(const h8*)&W[(size_t)(n0 + row) * 1024 + k0 + c * 8];
        }
        __syncthreads();
#pragma unroll
        for (int kk = 0; kk < 2; ++kk) {
            h8 af[4], bf[2];
#pragma unroll
            for (int mi = 0; mi < 4; ++mi)
                af[mi] = *(const h8*)&As[wr * 64 + mi * 16 + lr][kk * 32 + lg * 8];
#pragma unroll
            for (int ni = 0; ni < 2; ++ni)
                bf[ni] = *(const h8*)&Bs[wc * 32 + ni * 16 + lr][kk * 32 + lg * 8];
#pragma unroll
            for (int mi = 0; mi < 4; ++mi)
#pragma unroll
                for (int ni = 0; ni < 2; ++ni)
                    acc[mi][ni] = mfma16(af[mi], bf[ni], acc[mi][ni]);
        }
        __syncthreads();
    }

#pragma unroll
    for (int mi = 0; mi < 4; ++mi)
#pragma unroll
        for (int ni = 0; ni < 2; ++ni)
#pragma unroll
            for (int r = 0; r < 4; ++r) {
                int row = m0 + wr * 64 + mi * 16 + lg * 4 + r;
                int col = n0 + wc * 32 + ni * 16 + lr;
                float vv = acc[mi][ni][r] * scale;
                if (MODE == 0) {
                    int t = row >> 2, b = row & 3, h = col >> 6, d = col & 63;
                    ((_Float16*)Cv)[(((size_t)b * H_ + h) * T_ + t) * D_ + d] = (_Float16)vv;
                } else if (MODE == 1) {
                    int s = row >> 2, b = row & 3, h = col >> 6, d = col & 63;
                    ((_Float16*)Cv)[(((size_t)b * H_ + h) * D_ + d) * S_ + s] = (_Float16)vv;
                } else {
                    ((float*)Cv)[(size_t)row * E_ + col] = vv + bias[col];
                }
            }
}

// ---------------------------------------------------------------------------
// Fused attention, per (bh, 16-row t-tile), 512 thr = 8 waves.
// LDS ~37KB; __launch_bounds__(512,6): VGPR<=~84 -> 3 blocks/CU, keeps
// per-thread ILP (8 outstanding 16B loads in ph2).
//   ph1 : expS = mask ? 0 : exp(K.Q^T) (swapped MFMA) -> swizzled LDS f16
//   ph2 : batch-preload 8x bias float4 + 8x P h4 -> P = expS*exp(bias);
//         wave-local rowsum; attn = P*inv streamed out; P back to LDS.
//   ph3 : O = (P @ V)*inv, wave pairs split S, 4KB LDS reduce.
// Grid: 1D 4096, XCD-swizzled.
// ---------------------------------------------------------------------------
__global__ __launch_bounds__(512, 6) void fused_attn(
    const _Float16* __restrict__ qh, const _Float16* __restrict__ kh,
    const _Float16* __restrict__ vhT, const float* __restrict__ bias,
    const int* __restrict__ mask, float* __restrict__ attn,
    _Float16* __restrict__ oh)
{
    __shared__ _Float16 Pf[16 * 1024];   // swizzled, 32 KB
    __shared__ int aux_i[1024];          // mask (ph1) / PV partials (ph3)
    __shared__ float sinv16[16];
    char* Pb = (char*)Pf;

    const int bid = blockIdx.x;
    const int vid = (bid & 7) * 512 + (bid >> 3);   // 4096 % 8 == 0, bijective
    const int bh = vid >> 6;              // 0..63
    const int t0 = (vid & 63) * 16;       // 0..1008
    const int b = bh >> 4, h = bh & 15;
    const int tid = threadIdx.x;
    const int w = tid >> 6, l = tid & 63, lr = l & 15, lg = l >> 4;

    for (int i = tid; i < S_; i += 512) aux_i[i] = mask[(size_t)b * S_ + i];

    // Q fragments (B-operand): col t = lr, elems k
    const _Float16* qbase = qh + ((size_t)bh * T_ + t0) * D_;
    h8 qf0 = *(const h8*)&qbase[(size_t)lr * D_ + lg * 8];
    h8 qf1 = *(const h8*)&qbase[(size_t)lr * D_ + 32 + lg * 8];

    const _Float16* kbase = kh + (size_t)bh * S_ * D_;
    const int wbase = w * 128;            // this wave's s-stripe

    __syncthreads();                      // mask staged (ph1 reads it)

    // ---- phase 1: expS = mask?0:exp(qk) into LDS (MFMA layout, swizzled) --
#pragma unroll
    for (int sub = 0; sub < 8; ++sub) {
        int s0 = wbase + sub * 16;
        h8 kf0 = *(const h8*)&kbase[(size_t)(s0 + lr) * D_ + lg * 8];
        h8 kf1 = *(const h8*)&kbase[(size_t)(s0 + lr) * D_ + 32 + lg * 8];
        f4 c = (f4){0.f, 0.f, 0.f, 0.f};
        c = mfma16(kf0, qf0, c);
        c = mfma16(kf1, qf1, c);
        int4 mv = *(const int4*)&aux_i[s0 + lg * 4];
        h4 pv;
        pv[0] = mv.x ? (_Float16)0.f : (_Float16)__expf(c[0]);
        pv[1] = mv.y ? (_Float16)0.f : (_Float16)__expf(c[1]);
        pv[2] = mv.z ? (_Float16)0.f : (_Float16)__expf(c[2]);
        pv[3] = mv.w ? (_Float16)0.f : (_Float16)__expf(c[3]);
        int off = (lr * 2048 + (s0 + lg * 4) * 2) ^ ((lr & 7) << 4);
        *(h4*)(Pb + off) = pv;
    }
    __syncthreads();

    // ---- phase 2: batch-preload; P = expS*exp(bias); rowsum; stream attn --
    {
        const int rr = tid >> 5;          // 0..15 (row)
        const int c  = tid & 31;          // 0..31 (col group)
        const float* brow = bias + ((size_t)bh * T_ + t0 + rr) * S_;

        float4 bv[8];
#pragma unroll
        for (int j = 0; j < 8; ++j)
            bv[j] = *(const float4*)&brow[c * 4 + j * 128];

        h4 p[8];
#pragma unroll
        for (int j = 0; j < 8; ++j) {
            int off = (rr * 2048 + (c * 4 + j * 128) * 2) ^ ((rr & 7) << 4);
            p[j] = *(const h4*)(Pb + off);
        }

        h4 pn[8];
        float rs = 0.f;
#pragma unroll
        for (int j = 0; j < 8; ++j) {
            float p0 = (float)p[j][0] * __expf(bv[j].x);
            float p1 = (float)p[j][1] * __expf(bv[j].y);
            float p2 = (float)p[j][2] * __expf(bv[j].z);
            float p3 = (float)p[j][3] * __expf(bv[j].w);
            rs += (p0 + p1) + (p2 + p3);
            pn[j][0] = (_Float16)p0; pn[j][1] = (_Float16)p1;
            pn[j][2] = (_Float16)p2; pn[j][3] = (_Float16)p3;
        }

        rs += __shfl_xor(rs, 1); rs += __shfl_xor(rs, 2);
        rs += __shfl_xor(rs, 4); rs += __shfl_xor(rs, 8);
        rs += __shfl_xor(rs, 16);
        float inv = 1.0f / rs;
        if (c == 0) sinv16[rr] = inv;

#pragma unroll
        for (int j = 0; j < 8; ++j) {
            int off = (rr * 2048 + (c * 4 + j * 128) * 2) ^ ((rr & 7) << 4);
            *(h4*)(Pb + off) = pn[j];
        }
        float* arow = attn + ((size_t)bh * T_ + t0 + rr) * S_;
#pragma unroll
        for (int j = 0; j < 8; ++j) {
            float4 o = {(float)pn[j][0] * inv, (float)pn[j][1] * inv,
                        (float)pn[j][2] * inv, (float)pn[j][3] * inv};
            *(float4*)&arow[c * 4 + j * 128] = o;
        }
    }
    __syncthreads();

    // ---- phase 3: PV, wave pairs split S (512 each), LDS reduce ----
    {
        const int sh = w & 1, dbase = (w >> 1) * 16;
        const _Float16* vbase = vhT + (size_t)bh * D_ * S_;
        f4 acc = (f4){0.f, 0.f, 0.f, 0.f};
#pragma unroll 4
        for (int kc = 0; kc < 16; ++kc) {
            int s0 = sh * 512 + kc * 32;
            int off = (lr * 2048 + (s0 + lg * 8) * 2) ^ ((lr & 7) << 4);
            h8 pf = *(const h8*)(Pb + off);
            h8 vf = *(const h8*)&vbase[(size_t)(dbase + lr) * S_ + s0 + lg * 8];
            acc = mfma16(pf, vf, acc);
        }
        float* pvred = (float*)aux_i;     // reuse mask buffer (barrier above)
        if (sh) {
#pragma unroll
            for (int r = 0; r < 4; ++r)
                pvred[(lg * 4 + r) * 64 + dbase + lr] = acc[r];
        }
        __syncthreads();
        if (!sh) {
#pragma unroll
            for (int r = 0; r < 4; ++r) {
                int t = lg * 4 + r;
                float o = (acc[r] + pvred[t * 64 + dbase + lr]) * sinv16[t];
                oh[((size_t)(t0 + t) * B_ + b) * E_ + h * 64 + dbase + lr] = (_Float16)o;
            }
        }
    }
}

// ---------------------------------------------------------------------------
extern "C" void kernel_launch(void* const* d_in, const int* in_sizes, int n_in,
                              void* d_out, int out_size, void* d_ws, size_t ws_size,
                              hipStream_t stream)
{
    const float* q    = (const float*)d_in[0];
    const float* k    = (const float*)d_in[1];
    const float* v    = (const float*)d_in[2];
    const float* Wq   = (const float*)d_in[3];
    const float* Wk   = (const float*)d_in[4];
    const float* Wv   = (const float*)d_in[5];
    const float* Wp   = (const float*)d_in[6];
    const float* bp   = (const float*)d_in[7];
    const float* bias = (const float*)d_in[8];
    const int*   mask = (const int*)d_in[9];

    float* out  = (float*)d_out;               // (T,B,E) f32
    float* attn = out + (size_t)T_ * B_ * E_;  // (B,H,T,S) f32

    _Float16* qh   = (_Float16*)d_ws;          // (B,H,T,D)
    _Float16* kh   = qh + NH_;                 // (B,H,S,D)
    _Float16* vhT  = kh + NH_;                 // (B,H,D,S)
    _Float16* oh   = vhT + NH_;                // (T,B,E)
    _Float16* q16  = oh + NH_;                 // contiguous cvt_all dst
    _Float16* k16  = q16 + NH_;
    _Float16* v16  = k16 + NH_;
    _Float16* Wq16 = v16 + NH_;
    _Float16* Wk16 = Wq16 + EE_;
    _Float16* Wv16 = Wk16 + EE_;
    _Float16* Wp16 = Wv16 + EE_;

    dim3 blk(512);

    cvt_all<<<dim3(8192), dim3(256), 0, stream>>>(q, k, v, Wq, Wk, Wv, Wp, q16);

    proj_gemm<0><<<dim3(32, 8), blk, 0, stream>>>(q16, Wq16, nullptr, qh, SCALE_);
    proj_gemm<0><<<dim3(32, 8), blk, 0, stream>>>(k16, Wk16, nullptr, kh, 1.0f);
    proj_gemm<1><<<dim3(32, 8), blk, 0, stream>>>(v16, Wv16, nullptr, vhT, 1.0f);

    fused_attn<<<dim3(4096), blk, 0, stream>>>(qh, kh, vhT, bias, mask, attn, oh);

    proj_gemm<2><<<dim3(32, 8), blk, 0, stream>>>(oh, Wp16, bp, out, 1.0f);
}

// Round 9
// 258.191 us; speedup vs baseline: 3.8971x; 1.1594x over previous
//
#include <hip/hip_runtime.h>
#include <math.h>

// Problem constants
constexpr int T_ = 1024, S_ = 1024, B_ = 4, E_ = 1024, H_ = 16, D_ = 64;
constexpr float SCALE_ = 0.125f;                  // D^-0.5
constexpr size_t NH_ = (size_t)B_ * H_ * T_ * D_; // 4,194,304 elems
constexpr size_t EE_ = (size_t)E_ * E_;           // 1,048,576 elems

typedef _Float16 h8 __attribute__((ext_vector_type(8)));
typedef _Float16 h4 __attribute__((ext_vector_type(4)));
typedef float f4 __attribute__((ext_vector_type(4)));

__device__ inline f4 mfma16(h8 a, h8 b, f4 c) {
    return __builtin_amdgcn_mfma_f32_16x16x32_f16(a, b, c, 0, 0, 0);
}

// async global->LDS, 16B per lane; lds dest = wave-uniform base + lane*16
__device__ inline void gload_lds16(const void* g, void* l) {
    __builtin_amdgcn_global_load_lds(
        (const __attribute__((address_space(1))) void*)g,
        (__attribute__((address_space(3))) void*)l, 16, 0, 0);
}

// ---------------------------------------------------------------------------
// Fused f32 -> f16 converter for all 7 tensors (outputs contiguous in ws).
// ---------------------------------------------------------------------------
__global__ __launch_bounds__(256) void cvt_all(
    const float* __restrict__ q, const float* __restrict__ k,
    const float* __restrict__ v, const float* __restrict__ wq,
    const float* __restrict__ wk, const float* __restrict__ wv,
    const float* __restrict__ wp, _Float16* __restrict__ dst)
{
    const int i8 = blockIdx.x * 256 + threadIdx.x;   // 0 .. 2097151
    constexpr int BIG = (int)(NH_ / 8);              // 524288
    constexpr int WSZ = (int)(EE_ / 8);              // 131072
    const float* src;
    int loc;
    if (i8 < 3 * BIG) {
        int t = i8 / BIG; loc = i8 - t * BIG;
        src = t == 0 ? q : (t == 1 ? k : v);
    } else {
        int r = i8 - 3 * BIG;
        int t = r / WSZ; loc = r - t * WSZ;
        src = t == 0 ? wq : (t == 1 ? wk : (t == 2 ? wv : wp));
    }
    const float* p = src + (size_t)loc * 8;
    float4 a = *(const float4*)p;
    float4 b = *(const float4*)(p + 4);
    h8 o;
    o[0] = (_Float16)a.x; o[1] = (_Float16)a.y;
    o[2] = (_Float16)a.z; o[3] = (_Float16)a.w;
    o[4] = (_Float16)b.x; o[5] = (_Float16)b.y;
    o[6] = (_Float16)b.z; o[7] = (_Float16)b.w;
    *(h8*)&dst[(size_t)i8 * 8] = o;
}

// ---------------------------------------------------------------------------
// GEMM core: 64x128 tile, BK=64, 512 thr = 8 waves (2x4), wave tile 32x32.
// Staging via global_load_lds (16B/lane) into LINEAR LDS; bank spread via
// XOR swizzle applied on the GLOBAL source chunk and undone on the LDS read
// (chunk stored at c holds global chunk c^(row&7)).
// ---------------------------------------------------------------------------
template <typename EPI>
__device__ inline void gemm_core(
    const _Float16* __restrict__ A, const _Float16* __restrict__ W,
    int m0, int n0, EPI epi)
{
    __shared__ _Float16 As[64][64];    //  8 KB linear
    __shared__ _Float16 Bs[128][64];   // 16 KB linear

    const int tid = threadIdx.x;
    const int w = tid >> 6, l = tid & 63, lr = l & 15, lg = l >> 4;
    const int wr = w >> 2, wc = w & 3;

    const int srow = (w << 3) + (l >> 3);       // 0..63 staged row
    const int sg   = (l & 7) ^ (srow & 7);      // swizzled source chunk
    char* AsB = (char*)As;
    char* BsB = (char*)Bs;
    char* ldsA  = AsB + w * 1024;
    char* ldsB0 = BsB + w * 1024;
    char* ldsB1 = BsB + 8192 + w * 1024;

    f4 acc[2][2];
#pragma unroll
    for (int mi = 0; mi < 2; ++mi)
#pragma unroll
        for (int ni = 0; ni < 2; ++ni) acc[mi][ni] = (f4){0.f, 0.f, 0.f, 0.f};

    for (int k0 = 0; k0 < 1024; k0 += 64) {
        gload_lds16(&A[(size_t)(m0 + srow) * 1024 + k0 + sg * 8], ldsA);
        gload_lds16(&W[(size_t)(n0 + srow) * 1024 + k0 + sg * 8], ldsB0);
        gload_lds16(&W[(size_t)(n0 + 64 + srow) * 1024 + k0 + sg * 8], ldsB1);
        __syncthreads();   // drains vmcnt (compiler emits vmcnt(0) before barrier)
#pragma unroll
        for (int kk = 0; kk < 2; ++kk) {
            h8 af[2], bf[2];
#pragma unroll
            for (int mi = 0; mi < 2; ++mi) {
                int r = wr * 32 + mi * 16 + lr, kc = kk * 4 + lg;
                af[mi] = *(const h8*)(AsB + r * 128 + ((kc ^ (r & 7)) << 4));
            }
#pragma unroll
            for (int ni = 0; ni < 2; ++ni) {
                int r = wc * 32 + ni * 16 + lr, kc = kk * 4 + lg;
                bf[ni] = *(const h8*)(BsB + r * 128 + ((kc ^ (r & 7)) << 4));
            }
#pragma unroll
            for (int mi = 0; mi < 2; ++mi)
#pragma unroll
                for (int ni = 0; ni < 2; ++ni)
                    acc[mi][ni] = mfma16(af[mi], bf[ni], acc[mi][ni]);
        }
        __syncthreads();
    }

#pragma unroll
    for (int mi = 0; mi < 2; ++mi)
#pragma unroll
        for (int ni = 0; ni < 2; ++ni)
#pragma unroll
            for (int r = 0; r < 4; ++r) {
                int row = m0 + wr * 32 + mi * 16 + lg * 4 + r;
                int col = n0 + wc * 32 + ni * 16 + lr;
                epi(row, col, acc[mi][ni][r]);
            }
}

// ---------------------------------------------------------------------------
// Merged Q/K/V projection: blockIdx.z selects tensor. One launch = 1536
// blocks (6/CU) so CUs stay saturated across the whole stage.
// ---------------------------------------------------------------------------
__global__ __launch_bounds__(512) void qkv_gemm(
    const _Float16* __restrict__ q16, const _Float16* __restrict__ k16,
    const _Float16* __restrict__ v16, const _Float16* __restrict__ Wq16,
    const _Float16* __restrict__ Wk16, const _Float16* __restrict__ Wv16,
    _Float16* __restrict__ qh, _Float16* __restrict__ kh,
    _Float16* __restrict__ vhT)
{
    const int z = blockIdx.z;
    const _Float16* A = z == 0 ? q16 : (z == 1 ? k16 : v16);
    const _Float16* W = z == 0 ? Wq16 : (z == 1 ? Wk16 : Wv16);
    _Float16* C = z == 0 ? qh : (z == 1 ? kh : vhT);
    const float scale = (z == 0) ? SCALE_ : 1.0f;
    const int m0 = blockIdx.x * 64, n0 = blockIdx.y * 128;

    if (z < 2) {
        gemm_core(A, W, m0, n0, [&](int row, int col, float vv) {
            int t = row >> 2, b = row & 3, h = col >> 6, d = col & 63;
            C[(((size_t)b * H_ + h) * T_ + t) * D_ + d] = (_Float16)(vv * scale);
        });
    } else {
        gemm_core(A, W, m0, n0, [&](int row, int col, float vv) {
            int s = row >> 2, b = row & 3, h = col >> 6, d = col & 63;
            C[(((size_t)b * H_ + h) * D_ + d) * S_ + s] = (_Float16)vv;
        });
    }
}

// ---------------------------------------------------------------------------
// Output projection: out = oh @ Wp^T + bp  (f32 out)
// ---------------------------------------------------------------------------
__global__ __launch_bounds__(512) void out_gemm(
    const _Float16* __restrict__ oh, const _Float16* __restrict__ Wp16,
    const float* __restrict__ bp, float* __restrict__ out)
{
    const int m0 = blockIdx.x * 64, n0 = blockIdx.y * 128;
    gemm_core(oh, Wp16, m0, n0, [&](int row, int col, float vv) {
        out[(size_t)row * E_ + col] = vv + bp[col];
    });
}

// ---------------------------------------------------------------------------
// Fused attention, per (bh, 16-row t-tile), 512 thr = 8 waves.
//   prefetch: 8x bias float4 into VGPRs at kernel entry (HBM latency hides
//             under mask staging + ph1 QK^T).
//   ph1 : expS = mask?0:exp(K.Q^T) (swapped MFMA) -> swizzled LDS f16
//   ph2 : P = expS*exp(bias); wave-local rowsum; attn = P*inv nontemporal;
//         P back to LDS.
//   ph3 : O = (P @ V)*inv, wave pairs split S, 4KB LDS reduce.
// Grid: 1D 4096, XCD-swizzled.
// ---------------------------------------------------------------------------
__global__ __launch_bounds__(512, 6) void fused_attn(
    const _Float16* __restrict__ qh, const _Float16* __restrict__ kh,
    const _Float16* __restrict__ vhT, const float* __restrict__ bias,
    const int* __restrict__ mask, float* __restrict__ attn,
    _Float16* __restrict__ oh)
{
    __shared__ _Float16 Pf[16 * 1024];   // swizzled, 32 KB
    __shared__ int aux_i[1024];          // mask (ph1) / PV partials (ph3)
    __shared__ float sinv16[16];
    char* Pb = (char*)Pf;

    const int bid = blockIdx.x;
    const int vid = (bid & 7) * 512 + (bid >> 3);   // 4096 % 8 == 0, bijective
    const int bh = vid >> 6;              // 0..63
    const int t0 = (vid & 63) * 16;       // 0..1008
    const int b = bh >> 4, h = bh & 15;
    const int tid = threadIdx.x;
    const int w = tid >> 6, l = tid & 63, lr = l & 15, lg = l >> 4;

    // ---- bias prefetch: issue at entry, consumed in ph2 (T14) ----
    const int rr2 = tid >> 5;             // ph2 row
    const int c2  = tid & 31;             // ph2 col group
    const float* brow = bias + ((size_t)bh * T_ + t0 + rr2) * S_;
    f4 bv[8];
#pragma unroll
    for (int j = 0; j < 8; ++j)
        bv[j] = *(const f4*)&brow[c2 * 4 + j * 128];

    for (int i = tid; i < S_; i += 512) aux_i[i] = mask[(size_t)b * S_ + i];

    // Q fragments (B-operand): col t = lr, elems k
    const _Float16* qbase = qh + ((size_t)bh * T_ + t0) * D_;
    h8 qf0 = *(const h8*)&qbase[(size_t)lr * D_ + lg * 8];
    h8 qf1 = *(const h8*)&qbase[(size_t)lr * D_ + 32 + lg * 8];

    const _Float16* kbase = kh + (size_t)bh * S_ * D_;
    const int wbase = w * 128;            // this wave's s-stripe

    __syncthreads();                      // mask staged (ph1 reads it)

    // ---- phase 1: expS = mask?0:exp(qk) into LDS (MFMA layout, swizzled) --
#pragma unroll
    for (int sub = 0; sub < 8; ++sub) {
        int s0 = wbase + sub * 16;
        h8 kf0 = *(const h8*)&kbase[(size_t)(s0 + lr) * D_ + lg * 8];
        h8 kf1 = *(const h8*)&kbase[(size_t)(s0 + lr) * D_ + 32 + lg * 8];
        f4 c = (f4){0.f, 0.f, 0.f, 0.f};
        c = mfma16(kf0, qf0, c);
        c = mfma16(kf1, qf1, c);
        int4 mv = *(const int4*)&aux_i[s0 + lg * 4];
        h4 pv;
        pv[0] = mv.x ? (_Float16)0.f : (_Float16)__expf(c[0]);
        pv[1] = mv.y ? (_Float16)0.f : (_Float16)__expf(c[1]);
        pv[2] = mv.z ? (_Float16)0.f : (_Float16)__expf(c[2]);
        pv[3] = mv.w ? (_Float16)0.f : (_Float16)__expf(c[3]);
        int off = (lr * 2048 + (s0 + lg * 4) * 2) ^ ((lr & 7) << 4);
        *(h4*)(Pb + off) = pv;
    }
    __syncthreads();

    // ---- phase 2: P = expS*exp(bias); rowsum; nontemporal attn stream ----
    {
        h4 p[8];
#pragma unroll
        for (int j = 0; j < 8; ++j) {
            int off = (rr2 * 2048 + (c2 * 4 + j * 128) * 2) ^ ((rr2 & 7) << 4);
            p[j] = *(const h4*)(Pb + off);
        }

        h4 pn[8];
        float rs = 0.f;
#pragma unroll
        for (int j = 0; j < 8; ++j) {
            float p0 = (float)p[j][0] * __expf(bv[j][0]);
            float p1 = (float)p[j][1] * __expf(bv[j][1]);
            float p2 = (float)p[j][2] * __expf(bv[j][2]);
            float p3 = (float)p[j][3] * __expf(bv[j][3]);
            rs += (p0 + p1) + (p2 + p3);
            pn[j][0] = (_Float16)p0; pn[j][1] = (_Float16)p1;
            pn[j][2] = (_Float16)p2; pn[j][3] = (_Float16)p3;
        }

        rs += __shfl_xor(rs, 1); rs += __shfl_xor(rs, 2);
        rs += __shfl_xor(rs, 4); rs += __shfl_xor(rs, 8);
        rs += __shfl_xor(rs, 16);
        float inv = 1.0f / rs;
        if (c2 == 0) sinv16[rr2] = inv;

#pragma unroll
        for (int j = 0; j < 8; ++j) {
            int off = (rr2 * 2048 + (c2 * 4 + j * 128) * 2) ^ ((rr2 & 7) << 4);
            *(h4*)(Pb + off) = pn[j];
        }
        float* arow = attn + ((size_t)bh * T_ + t0 + rr2) * S_;
#pragma unroll
        for (int j = 0; j < 8; ++j) {
            f4 o = {(float)pn[j][0] * inv, (float)pn[j][1] * inv,
                    (float)pn[j][2] * inv, (float)pn[j][3] * inv};
            __builtin_nontemporal_store(o, (f4*)&arow[c2 * 4 + j * 128]);
        }
    }
    __syncthreads();

    // ---- phase 3: PV, wave pairs split S (512 each), LDS reduce ----
    {
        const int sh = w & 1, dbase = (w >> 1) * 16;
        const _Float16* vbase = vhT + (size_t)bh * D_ * S_;
        f4 acc = (f4){0.f, 0.f, 0.f, 0.f};
#pragma unroll 4
        for (int kc = 0; kc < 16; ++kc) {
            int s0 = sh * 512 + kc * 32;
            int off = (lr * 2048 + (s0 + lg * 8) * 2) ^ ((lr & 7) << 4);
            h8 pf = *(const h8*)(Pb + off);
            h8 vf = *(const h8*)&vbase[(size_t)(dbase + lr) * S_ + s0 + lg * 8];
            acc = mfma16(pf, vf, acc);
        }
        float* pvred = (float*)aux_i;     // reuse mask buffer (barrier above)
        if (sh) {
#pragma unroll
            for (int r = 0; r < 4; ++r)
                pvred[(lg * 4 + r) * 64 + dbase + lr] = acc[r];
        }
        __syncthreads();
        if (!sh) {
#pragma unroll
            for (int r = 0; r < 4; ++r) {
                int t = lg * 4 + r;
                float o = (acc[r] + pvred[t * 64 + dbase + lr]) * sinv16[t];
                oh[((size_t)(t0 + t) * B_ + b) * E_ + h * 64 + dbase + lr] = (_Float16)o;
            }
        }
    }
}

// ---------------------------------------------------------------------------
extern "C" void kernel_launch(void* const* d_in, const int* in_sizes, int n_in,
                              void* d_out, int out_size, void* d_ws, size_t ws_size,
                              hipStream_t stream)
{
    const float* q    = (const float*)d_in[0];
    const float* k    = (const float*)d_in[1];
    const float* v    = (const float*)d_in[2];
    const float* Wq   = (const float*)d_in[3];
    const float* Wk   = (const float*)d_in[4];
    const float* Wv   = (const float*)d_in[5];
    const float* Wp   = (const float*)d_in[6];
    const float* bp   = (const float*)d_in[7];
    const float* bias = (const float*)d_in[8];
    const int*   mask = (const int*)d_in[9];

    float* out  = (float*)d_out;               // (T,B,E) f32
    float* attn = out + (size_t)T_ * B_ * E_;  // (B,H,T,S) f32

    _Float16* qh   = (_Float16*)d_ws;          // (B,H,T,D)
    _Float16* kh   = qh + NH_;                 // (B,H,S,D)
    _Float16* vhT  = kh + NH_;                 // (B,H,D,S)
    _Float16* oh   = vhT + NH_;                // (T,B,E)
    _Float16* q16  = oh + NH_;                 // contiguous cvt_all dst
    _Float16* k16  = q16 + NH_;
    _Float16* v16  = k16 + NH_;
    _Float16* Wq16 = v16 + NH_;
    _Float16* Wk16 = Wq16 + EE_;
    _Float16* Wv16 = Wk16 + EE_;
    _Float16* Wp16 = Wv16 + EE_;

    dim3 blk(512);

    cvt_all<<<dim3(8192), dim3(256), 0, stream>>>(q, k, v, Wq, Wk, Wv, Wp, q16);

    qkv_gemm<<<dim3(64, 8, 3), blk, 0, stream>>>(
        q16, k16, v16, Wq16, Wk16, Wv16, qh, kh, vhT);

    fused_attn<<<dim3(4096), blk, 0, stream>>>(qh, kh, vhT, bias, mask, attn, oh);

    out_gemm<<<dim3(64, 8), blk, 0, stream>>>(oh, Wp16, bp, out);
}